// Round 11
// baseline (642.514 us; speedup 1.0000x reference)
//
#include <hip/hip_runtime.h>
#include <hip/hip_bf16.h>
#include <stdint.h>

// Qwen3.5 MoE block: router top-2 sparse dispatch + shared expert (SwiGLU), bf16 MFMA.
// B=2,S=1024 -> TOK=2048 tokens. H=2048, I=1408, IS=5632, E=8, K=2. Output f32.
// Round 11: down GEMM widened to 256x256 (32 MFMA/step like gateup) with the
// round-10 counted-vmcnt raw-barrier pipeline. Gateup unchanged (256x128).
#define TOK   2048
#define HDIM  2048
#define IDIM  1408
#define ISDIM 5632
#define NEXP  8

typedef float  f32x4  __attribute__((ext_vector_type(4)));
typedef short  bf16x8 __attribute__((ext_vector_type(8)));

__device__ __forceinline__ unsigned short f2b(float f) {
  union { float f; uint32_t u; } v; v.f = f;
  return (unsigned short)((v.u + 0x7fffu + ((v.u >> 16) & 1u)) >> 16); // RNE
}

// async global->LDS DMA, 16 B per lane: LDS dest wave-uniform base + lane*16.
__device__ __forceinline__ void async16(void* lds, const void* g) {
  __builtin_amdgcn_global_load_lds(
      (const __attribute__((address_space(1))) unsigned int*)g,
      (__attribute__((address_space(3))) unsigned int*)lds, 16, 0, 0);
}

// counted-vmcnt + raw barrier (no lgkm/vm drain); "memory" clobber pins LDS/VMEM ops.
#define VWAIT_BAR(N) asm volatile("s_waitcnt vmcnt(" #N ")\n\ts_barrier" ::: "memory")
#define VBAR()       asm volatile("s_barrier" ::: "memory")

// ---------------- router ----------------
__global__ __launch_bounds__(256) void router_kernel(
    const float* __restrict__ X, const float* __restrict__ GW,
    const float* __restrict__ SGW, int* __restrict__ cnt,
    int* __restrict__ tok_e, float* __restrict__ tok_w, float* __restrict__ sg)
{
  const int tkn = blockIdx.x, t = threadIdx.x;
  const float* xr = X + (size_t)tkn * HDIM;
  float a[NEXP + 1];
  #pragma unroll
  for (int e = 0; e <= NEXP; ++e) a[e] = 0.f;
  for (int h = t; h < HDIM; h += 256) {
    const float xv = xr[h];
    #pragma unroll
    for (int e = 0; e < NEXP; ++e) a[e] += xv * GW[e * HDIM + h];
    a[NEXP] += xv * SGW[h];
  }
  #pragma unroll
  for (int off = 32; off > 0; off >>= 1) {
    #pragma unroll
    for (int e = 0; e <= NEXP; ++e) a[e] += __shfl_down(a[e], off);
  }
  __shared__ float red[4][NEXP + 1];
  if ((t & 63) == 0) {
    #pragma unroll
    for (int e = 0; e <= NEXP; ++e) red[t >> 6][e] = a[e];
  }
  __syncthreads();
  if (t == 0) {
    float l[NEXP + 1];
    #pragma unroll
    for (int e = 0; e <= NEXP; ++e) l[e] = red[0][e] + red[1][e] + red[2][e] + red[3][e];
    int i1 = 0;
    #pragma unroll
    for (int e = 1; e < NEXP; ++e) if (l[e] > l[i1]) i1 = e;
    int i2 = (i1 == 0) ? 1 : 0;
    #pragma unroll
    for (int e = 0; e < NEXP; ++e) if (e != i1 && e != i2 && l[e] > l[i2]) i2 = e;
    const float w1 = 1.f / (1.f + __expf(l[i2] - l[i1]));   // softmax+top2+renorm == sigmoid(diff)
    tok_e[tkn * 2 + 0] = i1; tok_e[tkn * 2 + 1] = i2;
    tok_w[tkn * 2 + 0] = w1; tok_w[tkn * 2 + 1] = 1.f - w1;
    atomicAdd(&cnt[i1], 1); atomicAdd(&cnt[i2], 1);
    sg[tkn] = 1.f / (1.f + __expf(-l[NEXP]));
  }
}

__global__ void scan_kernel(const int* __restrict__ cnt, int* __restrict__ offs) {
  if (threadIdx.x == 0) {
    int r = 0;
    for (int e = 0; e < NEXP; ++e) { offs[e] = r; r += cnt[e]; }
  }
}

__global__ __launch_bounds__(256) void build_kernel(
    const int* __restrict__ tok_e, const float* __restrict__ tok_w,
    const int* __restrict__ offs, int* __restrict__ cur,
    int* __restrict__ list, float* __restrict__ wl)
{
  const int tkn = blockIdx.x * 256 + threadIdx.x;
  if (tkn >= TOK) return;
  #pragma unroll
  for (int k = 0; k < 2; ++k) {
    const int e = tok_e[tkn * 2 + k];
    const int pos = atomicAdd(&cur[e], 1);
    const int slot = offs[e] + pos;
    list[slot] = tkn;
    wl[slot] = tok_w[tkn * 2 + k];
  }
}

// ---------------- preprocessing ----------------
__global__ __launch_bounds__(256) void cvt_kernel(
    const float* __restrict__ src, unsigned short* __restrict__ dst, int n4)
{
  const int i = blockIdx.x * 512 + threadIdx.x;
  #pragma unroll
  for (int p = 0; p < 2; ++p) {
    const int j = i + p * 256;
    if (j < n4) {
      const float4 v = ((const float4*)src)[j];
      ushort4 b; b.x = f2b(v.x); b.y = f2b(v.y); b.z = f2b(v.z); b.w = f2b(v.w);
      ((ushort4*)dst)[j] = b;
    }
  }
}

// f32 [R][C] -> bf16 [C][R], per-z matrix. grid (C/64, R/64, nmat)
__global__ __launch_bounds__(256) void transpose_cvt_kernel(
    const float* __restrict__ src, unsigned short* __restrict__ dst,
    const int R, const int C)
{
  __shared__ unsigned short tile[64][72];
  const size_t mat = (size_t)blockIdx.z * R * C;
  const int c0 = blockIdx.x * 64, r0 = blockIdx.y * 64;
  const int t = threadIdx.x;
  const int rr = t >> 4, cc = (t & 15) * 4;
  #pragma unroll
  for (int p = 0; p < 4; ++p) {
    const int r = rr + p * 16;
    const float4 v = *(const float4*)(src + mat + (size_t)(r0 + r) * C + c0 + cc);
    tile[cc + 0][r] = f2b(v.x);
    tile[cc + 1][r] = f2b(v.y);
    tile[cc + 2][r] = f2b(v.z);
    tile[cc + 3][r] = f2b(v.w);
  }
  __syncthreads();
  #pragma unroll
  for (int p = 0; p < 2; ++p) {
    const int id = p * 256 + t;
    const int c = id >> 3, q = id & 7;
    const uint4 v = *(const uint4*)&tile[c][q * 8];
    *(uint4*)(dst + mat + (size_t)(c0 + c) * R + r0 + q * 8) = v;
  }
}

// ---------------- FUSED gateup: 256x128 tile, 8 waves, BK=32, counted-vmcnt dbuf ----------------
// (unchanged from round 10)
__global__ __launch_bounds__(512) void gateup_fused_kernel(
    const unsigned short* __restrict__ Xb,
    const unsigned short* __restrict__ Wshg, const unsigned short* __restrict__ Wshu,
    const unsigned short* __restrict__ Wexg, const unsigned short* __restrict__ Wexu,
    unsigned short* __restrict__ shb, unsigned short* __restrict__ hb,
    const int* __restrict__ list, const int* __restrict__ offs, const int* __restrict__ cnt)
{
  __shared__ char smem[65536];

  const int xcd = blockIdx.x & 7;
  const int local = blockIdx.x >> 3;
  const int c = xcd + 8 * (local >> 3);
  const int mt = local & 7;
  if (c >= 132) return;
  const int t = threadIdx.x;

  int rowbase, mcnt, n0, N, gather;
  const unsigned short *Wg, *Wu;
  unsigned short* Cout;
  if (c < 44) {
    N = ISDIM; n0 = c * 128; rowbase = mt * 256; mcnt = 256; gather = 0;
    Wg = Wshg; Wu = Wshu; Cout = shb;
  } else {
    const int cE = c - 44;
    const int e = cE / 11, n = cE % 11;
    mcnt = cnt[e] - mt * 256;
    if (mcnt <= 0) return;
    N = IDIM; n0 = n * 128; rowbase = offs[e] + mt * 256; gather = 1;
    Wg = Wexg + (size_t)e * IDIM * HDIM;
    Wu = Wexu + (size_t)e * IDIM * HDIM;
    Cout = hb;
  }

  const int wid = t >> 6, lane = t & 63;
  const int wm = wid >> 1, wn = wid & 1;
  const int lcol = lane & 15, lk = lane >> 4;

  f32x4 accg[4][4], accu[4][4];
  #pragma unroll
  for (int i = 0; i < 4; ++i)
    #pragma unroll
    for (int j = 0; j < 4; ++j) { accg[i][j] = {0.f,0.f,0.f,0.f}; accu[i][j] = {0.f,0.f,0.f,0.f}; }

  int arow[2], akoff[2];
  #pragma unroll
  for (int p = 0; p < 2; ++p) {
    const int s = p * 512 + t;
    const int m = s >> 2;
    akoff[p] = (((s & 3) ^ ((m >> 1) & 3)) << 3);
    arow[p] = gather ? list[rowbase + m] : (rowbase + m);   // list zero-padded (4608)
  }
  const int albase0 = (t & 448) * 16;
  const int albase1 = (512 + (t & 448)) * 16;
  const int bmrow = n0 + (t >> 2);
  const int bkoff = (((t & 3) ^ (((t >> 2) >> 1) & 3)) << 3);
  const int blbase = (t & 448) * 16;

#define STAGE_GU(BUF, K0) do {                                                    \
    async16(smem + (BUF) + albase0,        Xb + (size_t)arow[0] * HDIM + (K0) + akoff[0]); \
    async16(smem + (BUF) + albase1,        Xb + (size_t)arow[1] * HDIM + (K0) + akoff[1]); \
    async16(smem + (BUF) + 16384 + blbase, Wg + (size_t)bmrow * HDIM + (K0) + bkoff); \
    async16(smem + (BUF) + 24576 + blbase, Wu + (size_t)bmrow * HDIM + (K0) + bkoff); \
  } while (0)

#define COMPUTE_GU(BUF) do {                                                      \
    bf16x8 af[4], bg[4], bu[4];                                                   \
    _Pragma("unroll")                                                             \
    for (int fm = 0; fm < 4; ++fm) {                                              \
      const int m = wm * 64 + fm * 16 + lcol;                                     \
      af[fm] = *(const bf16x8*)(smem + (BUF) + m * 64 + (((lk ^ ((m >> 1) & 3)) & 3) << 4)); \
    }                                                                             \
    _Pragma("unroll")                                                             \
    for (int fn = 0; fn < 4; ++fn) {                                              \
      const int n = wn * 64 + fn * 16 + lcol;                                     \
      const int ra = n * 64 + (((lk ^ ((n >> 1) & 3)) & 3) << 4);                 \
      bg[fn] = *(const bf16x8*)(smem + (BUF) + 16384 + ra);                       \
      bu[fn] = *(const bf16x8*)(smem + (BUF) + 24576 + ra);                       \
    }                                                                             \
    _Pragma("unroll")                                                             \
    for (int fm = 0; fm < 4; ++fm)                                                \
      _Pragma("unroll")                                                           \
      for (int fn = 0; fn < 4; ++fn) {                                            \
        accg[fm][fn] = __builtin_amdgcn_mfma_f32_16x16x32_bf16(af[fm], bg[fn], accg[fm][fn], 0, 0, 0); \
        accu[fm][fn] = __builtin_amdgcn_mfma_f32_16x16x32_bf16(af[fm], bu[fn], accu[fm][fn], 0, 0, 0); \
      } } while (0)

  STAGE_GU(0, 0);
  for (int it = 0; it < 31; ++it) {
    STAGE_GU(32768, (2 * it + 1) * 32);
    VWAIT_BAR(4);
    COMPUTE_GU(0);
    VBAR();
    STAGE_GU(0, (2 * it + 2) * 32);
    VWAIT_BAR(4);
    COMPUTE_GU(32768);
    VBAR();
  }
  STAGE_GU(32768, 63 * 32);
  VWAIT_BAR(4);
  COMPUTE_GU(0);
  VBAR();
  VWAIT_BAR(0);
  COMPUTE_GU(32768);
#undef STAGE_GU
#undef COMPUTE_GU

  #pragma unroll
  for (int fm = 0; fm < 4; ++fm) {
    #pragma unroll
    for (int fn = 0; fn < 4; ++fn) {
      const int col = n0 + wn * 64 + fn * 16 + lcol;
      #pragma unroll
      for (int r = 0; r < 4; ++r) {
        const int lrow = wm * 64 + fm * 16 + lk * 4 + r;
        if (lrow < mcnt) {
          const float gv = accg[fm][fn][r];
          const float uv = accu[fm][fn][r];
          const float hv = gv * uv / (1.f + __expf(-gv));
          Cout[(size_t)(rowbase + lrow) * N + col] = f2b(hv);
        }
      }
    }
  }
}

// ---------------- FUSED down: 256x256 tile, 8 waves (128x64 each), BK=32, counted-vmcnt ----------------
// LDS/buffer: A 256x32 (16K) + B 256x32 (16K) = 32K; x2 = 64K -> 2 blk/CU.
// Columns (96): 0..31 shared (pn=c&7, ksp=c>>3; 44 steps), 32..95 expert (e=cE>>3, pn=cE&7; 44 steps).
// grid 768 = 8 xcd x 12 col-slots x 8 mt. All atomicAdd into zeroed out.
__global__ __launch_bounds__(512) void down_fused_kernel(
    const unsigned short* __restrict__ shb, const unsigned short* __restrict__ hb,
    const unsigned short* __restrict__ WdshT, const unsigned short* __restrict__ WdexT,
    float* __restrict__ out,
    const int* __restrict__ list, const float* __restrict__ wl, const float* __restrict__ sg,
    const int* __restrict__ offs, const int* __restrict__ cnt)
{
  __shared__ char smem[65536];

  const int xcd = blockIdx.x & 7;
  const int local = blockIdx.x >> 3;          // 0..95
  const int c = xcd + 8 * (local >> 3);       // 0..95
  const int mt = local & 7;
  const int t = threadIdx.x;

  int rowbase, mcnt, n0, K, kbeg, em;
  const unsigned short *Ap, *Bp;
  if (c < 32) {                // shared, splitK=4 (44 steps each)
    const int pn = c & 7, ksp = c >> 3;
    rowbase = mt * 256; mcnt = 256; n0 = pn * 256;
    K = ISDIM; kbeg = ksp * 44; em = 0;
    Ap = shb; Bp = WdshT;
  } else {                     // expert (44 steps)
    const int cE = c - 32;
    const int e = cE >> 3, n = cE & 7;
    mcnt = cnt[e] - mt * 256;
    if (mcnt <= 0) return;
    rowbase = offs[e] + mt * 256; n0 = n * 256;
    K = IDIM; kbeg = 0; em = 1;
    Ap = hb; Bp = WdexT + (size_t)e * HDIM * IDIM;
  }

  const int wid = t >> 6, lane = t & 63;
  const int wm = wid >> 2, wn = wid & 3;      // wave: 128 rows x 64 cols
  const int lcol = lane & 15, lk = lane >> 4;

  f32x4 acc[8][4];
  #pragma unroll
  for (int i = 0; i < 8; ++i)
    #pragma unroll
    for (int j = 0; j < 4; ++j) acc[i][j] = {0.f,0.f,0.f,0.f};

  // staging decomposition (shared by A and B): s = p*512+t; m = s>>2 (0..255); g = s&3
  int amrow[2], bmrow[2], koff[2];
  #pragma unroll
  for (int p = 0; p < 2; ++p) {
    const int s = p * 512 + t;
    const int m = s >> 2;
    koff[p] = (((s & 3) ^ ((m >> 1) & 3)) << 3);
    int rw = rowbase + m;
    if (em && rw > 4223) rw = 4223;    // clamp: hb has 4224 row slots
    amrow[p] = rw;
    bmrow[p] = n0 + m;
  }
  const int lbase0 = (t & 448) * 16;
  const int lbase1 = 8192 + (t & 448) * 16;

#define STAGE_D(BUF, K0) do {                                                     \
    async16(smem + (BUF) + lbase0,         Ap + (size_t)amrow[0] * K + (K0) + koff[0]); \
    async16(smem + (BUF) + lbase1,         Ap + (size_t)amrow[1] * K + (K0) + koff[1]); \
    async16(smem + (BUF) + 16384 + lbase0, Bp + (size_t)bmrow[0] * K + (K0) + koff[0]); \
    async16(smem + (BUF) + 16384 + lbase1, Bp + (size_t)bmrow[1] * K + (K0) + koff[1]); \
  } while (0)

#define COMPUTE_D(BUF) do {                                                       \
    bf16x8 af[8], bfr[4];                                                         \
    _Pragma("unroll")                                                             \
    for (int fm = 0; fm < 8; ++fm) {                                              \
      const int m = wm * 128 + fm * 16 + lcol;                                    \
      af[fm] = *(const bf16x8*)(smem + (BUF) + m * 64 + (((lk ^ ((m >> 1) & 3)) & 3) << 4)); \
    }                                                                             \
    _Pragma("unroll")                                                             \
    for (int fn = 0; fn < 4; ++fn) {                                              \
      const int n = wn * 64 + fn * 16 + lcol;                                     \
      bfr[fn] = *(const bf16x8*)(smem + (BUF) + 16384 + n * 64 + (((lk ^ ((n >> 1) & 3)) & 3) << 4)); \
    }                                                                             \
    _Pragma("unroll")                                                             \
    for (int fm = 0; fm < 8; ++fm)                                                \
      _Pragma("unroll")                                                           \
      for (int fn = 0; fn < 4; ++fn)                                              \
        acc[fm][fn] = __builtin_amdgcn_mfma_f32_16x16x32_bf16(af[fm], bfr[fn], acc[fm][fn], 0, 0, 0); \
  } while (0)

  // 44 steps: prologue + 21 double-iterations + epilogue
  const int kb = kbeg * 32;
  STAGE_D(0, kb);
  for (int it = 0; it < 21; ++it) {
    STAGE_D(32768, kb + (2 * it + 1) * 32);
    VWAIT_BAR(4);
    COMPUTE_D(0);
    VBAR();
    STAGE_D(0, kb + (2 * it + 2) * 32);
    VWAIT_BAR(4);
    COMPUTE_D(32768);
    VBAR();
  }
  STAGE_D(32768, kb + 43 * 32);
  VWAIT_BAR(4);
  COMPUTE_D(0);
  VBAR();
  VWAIT_BAR(0);
  COMPUTE_D(32768);
#undef STAGE_D
#undef COMPUTE_D

  #pragma unroll
  for (int fm = 0; fm < 8; ++fm) {
    #pragma unroll
    for (int fn = 0; fn < 4; ++fn) {
      const int col = n0 + wn * 64 + fn * 16 + lcol;
      #pragma unroll
      for (int r = 0; r < 4; ++r) {
        const int lrow = wm * 128 + fm * 16 + lk * 4 + r;
        if (lrow < mcnt) {
          const float v = acc[fm][fn][r];
          const int sl = rowbase + lrow;
          const int orow = em ? list[sl] : sl;
          const float sc = em ? wl[sl] : sg[sl];
          atomicAdd(out + (size_t)orow * HDIM + col, sc * v);
        }
      }
    }
  }
}

// ================= round-4 path (ws in [136MB, 182MB)) =================
template<bool GATHER>
__global__ __launch_bounds__(256) void gateup_bf_kernel(
    const unsigned short* __restrict__ Xb,
    const unsigned short* __restrict__ WgT, const unsigned short* __restrict__ WuT,
    unsigned short* __restrict__ Cout,
    const int* __restrict__ list, const int* __restrict__ offs,
    const int* __restrict__ cnt, const int N, const int NT)
{
  __shared__ char smem[49152];
  char* sA  = smem;
  char* sBg = smem + 16384;
  char* sBu = smem + 32768;
  int wg = blockIdx.x;
  wg = (wg & 7) * (gridDim.x >> 3) + (wg >> 3);
  const int mt = wg & 15;
  const int pn = wg >> 4;
  const int t = threadIdx.x;
  int rowbase, mcnt, n0;
  const unsigned short *Wg, *Wu;
  if (GATHER) {
    const int e = pn / NT, n = pn % NT;
    mcnt = cnt[e] - mt * 128;
    if (mcnt <= 0) return;
    rowbase = offs[e] + mt * 128;
    n0 = n * 128;
    Wg = WgT + (size_t)e * N * HDIM;
    Wu = WuT + (size_t)e * N * HDIM;
  } else {
    rowbase = mt * 128; mcnt = 128; n0 = pn * 128;
    Wg = WgT; Wu = WuT;
  }
  const int w = t >> 6, lane = t & 63;
  const int wr = w >> 1, wc = w & 1;
  const int lcol = lane & 15, lk = lane >> 4;
  f32x4 accg[4][4], accu[4][4];
  #pragma unroll
  for (int i = 0; i < 4; ++i)
    #pragma unroll
    for (int j = 0; j < 4; ++j) { accg[i][j] = {0.f,0.f,0.f,0.f}; accu[i][j] = {0.f,0.f,0.f,0.f}; }
  int arow[4], bm[4], koff[4];
  #pragma unroll
  for (int p = 0; p < 4; ++p) {
    const int s = p * 256 + t;
    const int m = s >> 3;
    bm[p] = m;
    koff[p] = ((s & 7) ^ (m & 7)) << 3;
    arow[p] = GATHER ? list[rowbase + m] : (rowbase + m);
  }
  const int KSTEPS = HDIM / 64;
  for (int kt = 0; kt < KSTEPS; ++kt) {
    const int k0 = kt * 64;
    if (kt) __syncthreads();
    #pragma unroll
    for (int p = 0; p < 4; ++p) {
      const int lb = (p * 256 + (t & 192)) * 16;
      async16(sA  + lb, Xb + (size_t)arow[p] * HDIM + k0 + koff[p]);
      async16(sBg + lb, Wg + (size_t)(n0 + bm[p]) * HDIM + k0 + koff[p]);
      async16(sBu + lb, Wu + (size_t)(n0 + bm[p]) * HDIM + k0 + koff[p]);
    }
    __syncthreads();
    #pragma unroll
    for (int ks = 0; ks < 2; ++ks) {
      bf16x8 af[4], bg[4], bu[4];
      #pragma unroll
      for (int fm = 0; fm < 4; ++fm) {
        const int m = wr * 64 + fm * 16 + lcol;
        af[fm] = *(const bf16x8*)(sA + m * 128 + (((ks * 4 + lk) ^ (m & 7)) << 4));
      }
      #pragma unroll
      for (int fn = 0; fn < 4; ++fn) {
        const int n = wc * 64 + fn * 16 + lcol;
        const int ra = n * 128 + (((ks * 4 + lk) ^ (n & 7)) << 4);
        bg[fn] = *(const bf16x8*)(sBg + ra);
        bu[fn] = *(const bf16x8*)(sBu + ra);
      }
      #pragma unroll
      for (int fm = 0; fm < 4; ++fm)
        #pragma unroll
        for (int fn = 0; fn < 4; ++fn) {
          accg[fm][fn] = __builtin_amdgcn_mfma_f32_16x16x32_bf16(af[fm], bg[fn], accg[fm][fn], 0, 0, 0);
          accu[fm][fn] = __builtin_amdgcn_mfma_f32_16x16x32_bf16(af[fm], bu[fn], accu[fm][fn], 0, 0, 0);
        }
    }
  }
  #pragma unroll
  for (int fm = 0; fm < 4; ++fm) {
    #pragma unroll
    for (int fn = 0; fn < 4; ++fn) {
      const int col = n0 + wc * 64 + fn * 16 + lcol;
      #pragma unroll
      for (int r = 0; r < 4; ++r) {
        const int lrow = wr * 64 + fm * 16 + lk * 4 + r;
        if (lrow < mcnt) {
          const float gv = accg[fm][fn][r];
          const float uv = accu[fm][fn][r];
          Cout[(size_t)(rowbase + lrow) * N + col] = f2b(gv * uv / (1.f + __expf(-gv)));
        }
      }
    }
  }
}

template<bool EXPERT, int KSPLIT>
__global__ __launch_bounds__(256) void down_bf_kernel(
    const unsigned short* __restrict__ Abuf,
    const unsigned short* __restrict__ BT,
    float* __restrict__ out,
    const int* __restrict__ list, const float* __restrict__ wl,
    const int* __restrict__ offs, const int* __restrict__ cnt,
    const int K, const int ktps)
{
  __shared__ char smem[32768];
  char* sA = smem;
  char* sB = smem + 16384;
  int wg = blockIdx.x;
  wg = (wg & 7) * (gridDim.x >> 3) + (wg >> 3);
  const int ksp = wg % KSPLIT;
  const int mt  = (wg / KSPLIT) & 15;
  const int pn  = wg / (KSPLIT * 16);
  const int t = threadIdx.x;
  int rowbase, mcnt, n0;
  const unsigned short* Bm;
  if (EXPERT) {
    const int e = pn >> 4, n = pn & 15;
    mcnt = cnt[e] - mt * 128;
    if (mcnt <= 0) return;
    rowbase = offs[e] + mt * 128;
    n0 = n * 128;
    Bm = BT + (size_t)e * HDIM * K;
  } else {
    rowbase = mt * 128; mcnt = 128; n0 = pn * 128;
    Bm = BT;
  }
  const int w = t >> 6, lane = t & 63;
  const int wr = w >> 1, wc = w & 1;
  const int lcol = lane & 15, lk = lane >> 4;
  f32x4 acc[4][4];
  #pragma unroll
  for (int i = 0; i < 4; ++i)
    #pragma unroll
    for (int j = 0; j < 4; ++j) acc[i][j] = {0.f,0.f,0.f,0.f};
  int bm[4], koff[4];
  #pragma unroll
  for (int p = 0; p < 4; ++p) {
    const int s = p * 256 + t;
    const int m = s >> 3;
    bm[p] = m;
    koff[p] = ((s & 7) ^ (m & 7)) << 3;
  }
  const int kbeg = ksp * ktps, kend = kbeg + ktps;
  for (int kt = kbeg; kt < kend; ++kt) {
    const int k0 = kt * 64;
    if (kt != kbeg) __syncthreads();
    #pragma unroll
    for (int p = 0; p < 4; ++p) {
      const int lb = (p * 256 + (t & 192)) * 16;
      async16(sA + lb, Abuf + (size_t)(rowbase + bm[p]) * K + k0 + koff[p]);
      async16(sB + lb, Bm + (size_t)(n0 + bm[p]) * K + k0 + koff[p]);
    }
    __syncthreads();
    #pragma unroll
    for (int ks = 0; ks < 2; ++ks) {
      bf16x8 af[4], bfr[4];
      #pragma unroll
      for (int fm = 0; fm < 4; ++fm) {
        const int m = wr * 64 + fm * 16 + lcol;
        af[fm] = *(const bf16x8*)(sA + m * 128 + (((ks * 4 + lk) ^ (m & 7)) << 4));
      }
      #pragma unroll
      for (int fn = 0; fn < 4; ++fn) {
        const int n = wc * 64 + fn * 16 + lcol;
        bfr[fn] = *(const bf16x8*)(sB + n * 128 + (((ks * 4 + lk) ^ (n & 7)) << 4));
      }
      #pragma unroll
      for (int fm = 0; fm < 4; ++fm)
        #pragma unroll
        for (int fn = 0; fn < 4; ++fn)
          acc[fm][fn] = __builtin_amdgcn_mfma_f32_16x16x32_bf16(af[fm], bfr[fn], acc[fm][fn], 0, 0, 0);
    }
  }
  #pragma unroll
  for (int fm = 0; fm < 4; ++fm) {
    #pragma unroll
    for (int fn = 0; fn < 4; ++fn) {
      const int col = n0 + wc * 64 + fn * 16 + lcol;
      #pragma unroll
      for (int r = 0; r < 4; ++r) {
        const int lrow = wr * 64 + fm * 16 + lk * 4 + r;
        if (lrow < mcnt) {
          const float v = acc[fm][fn][r];
          if (EXPERT) {
            const int slot = rowbase + lrow;
            atomicAdd(out + (size_t)list[slot] * HDIM + col, wl[slot] * v);
          } else {
            const int row = rowbase + lrow;
            atomicAdd(out + (size_t)row * HDIM + col, wl[row] * v);
          }
        }
      }
    }
  }
}

extern "C" void kernel_launch(void* const* d_in, const int* in_sizes, int n_in,
                              void* d_out, int out_size, void* d_ws, size_t ws_size,
                              hipStream_t stream)
{
  const float* x       = (const float*)d_in[0];
  const float* gate_w  = (const float*)d_in[1];
  const float* w_gate  = (const float*)d_in[2];
  const float* w_up    = (const float*)d_in[3];
  const float* w_down  = (const float*)d_in[4];
  const float* sw_gate = (const float*)d_in[5];
  const float* sw_up   = (const float*)d_in[6];
  const float* sw_down = (const float*)d_in[7];
  const float* sgw     = (const float*)d_in[8];

  float* out = (float*)d_out;   // f32 [TOK][H]; pure accumulator (zeroed)
  char* ws = (char*)d_ws;

  const size_t NEED_FUSED = 182000000;
  const size_t NEED_R4    = 136000000;

  if (ws_size >= NEED_FUSED) {
    unsigned short* Xb  = (unsigned short*)ws;                      //   8,388,608
    unsigned short* W1  = (unsigned short*)(ws + 8388608);          //  23,068,672 shG^T / later shDown^T
    unsigned short* W2  = (unsigned short*)(ws + 31457280);         //  23,068,672 shU^T
    unsigned short* W3  = (unsigned short*)(ws + 54525952);         //  46,137,344 exG^T / later exDown^T
    unsigned short* W4  = (unsigned short*)(ws + 100663296);        //  46,137,344 exU^T
    unsigned short* shb = (unsigned short*)(ws + 146800640);        //  23,068,672
    unsigned short* hb  = (unsigned short*)(ws + 169869312);        //  11,894,784
    char* meta = ws + 181764096;
    int*   cnt   = (int*)(meta);
    int*   cur   = (int*)(meta + 256);
    int*   offs  = (int*)(meta + 512);
    int*   list  = (int*)(meta + 768);                 // 4608 ints (zero-padded)
    float* wl    = (float*)(meta + 768 + 18432);       // 4608 floats (zero-padded)
    int*   tok_e = (int*)(meta + 768 + 2 * 18432);
    float* tok_w = (float*)(meta + 768 + 2 * 18432 + 16384);
    float* sg    = (float*)(meta + 768 + 2 * 18432 + 32768);

    hipMemsetAsync(meta, 0, 768 + 2 * 18432, stream);
    hipMemsetAsync(out, 0, (size_t)TOK * HDIM * 4, stream);

    cvt_kernel<<<TOK * HDIM / 4 / 512, 256, 0, stream>>>(x, Xb, TOK * HDIM / 4);
    router_kernel<<<TOK, 256, 0, stream>>>(x, gate_w, sgw, cnt, tok_e, tok_w, sg);
    scan_kernel<<<1, 64, 0, stream>>>(cnt, offs);
    build_kernel<<<8, 256, 0, stream>>>(tok_e, tok_w, offs, cur, list, wl);

    transpose_cvt_kernel<<<dim3(ISDIM / 64, HDIM / 64, 1), 256, 0, stream>>>(sw_gate, W1, HDIM, ISDIM);
    transpose_cvt_kernel<<<dim3(ISDIM / 64, HDIM / 64, 1), 256, 0, stream>>>(sw_up,   W2, HDIM, ISDIM);
    transpose_cvt_kernel<<<dim3(IDIM / 64, HDIM / 64, NEXP), 256, 0, stream>>>(w_gate, W3, HDIM, IDIM);
    transpose_cvt_kernel<<<dim3(IDIM / 64, HDIM / 64, NEXP), 256, 0, stream>>>(w_up,   W4, HDIM, IDIM);

    // grid 1088 = 8 xcd x 17 col-slots x 8 mt (cols >=132 return), 512 threads
    gateup_fused_kernel<<<1088, 512, 0, stream>>>(Xb, W1, W2, W3, W4, shb, hb, list, offs, cnt);

    transpose_cvt_kernel<<<dim3(HDIM / 64, ISDIM / 64, 1), 256, 0, stream>>>(sw_down, W1, ISDIM, HDIM);
    transpose_cvt_kernel<<<dim3(HDIM / 64, IDIM / 64, NEXP), 256, 0, stream>>>(w_down, W3, IDIM, HDIM);

    // grid 768 = 8 xcd x 12 col-slots x 8 mt, 512 threads
    down_fused_kernel<<<768, 512, 0, stream>>>(shb, hb, W1, W3, out, list, wl, sg, offs, cnt);
  } else if (ws_size >= NEED_R4) {
    unsigned short* Xb   = (unsigned short*)ws;
    unsigned short* R1a  = (unsigned short*)(ws + 8388608);
    unsigned short* R1b  = (unsigned short*)(ws + 54525952);
    unsigned short* shb  = (unsigned short*)(ws + 100663296);
    unsigned short* hb   = (unsigned short*)(ws + 123731968);
    char* meta = ws + 135626752;
    int*   cnt   = (int*)(meta);
    int*   cur   = (int*)(meta + 256);
    int*   offs  = (int*)(meta + 512);
    int*   list  = (int*)(meta + 768);
    float* wl    = (float*)(meta + 768 + 17152);
    int*   tok_e = (int*)(meta + 768 + 2 * 17152);
    float* tok_w = (float*)(meta + 768 + 2 * 17152 + 16384);
    float* sg    = (float*)(meta + 768 + 2 * 17152 + 32768);

    hipMemsetAsync(meta, 0, 768 + 2 * 17152, stream);
    hipMemsetAsync(out, 0, (size_t)TOK * HDIM * 4, stream);

    cvt_kernel<<<TOK * HDIM / 4 / 512, 256, 0, stream>>>(x, Xb, TOK * HDIM / 4);
    router_kernel<<<TOK, 256, 0, stream>>>(x, gate_w, sgw, cnt, tok_e, tok_w, sg);
    scan_kernel<<<1, 64, 0, stream>>>(cnt, offs);
    build_kernel<<<8, 256, 0, stream>>>(tok_e, tok_w, offs, cur, list, wl);

    transpose_cvt_kernel<<<dim3(ISDIM / 64, HDIM / 64, 1), 256, 0, stream>>>(sw_gate, R1a, HDIM, ISDIM);
    transpose_cvt_kernel<<<dim3(ISDIM / 64, HDIM / 64, 1), 256, 0, stream>>>(sw_up,   R1b, HDIM, ISDIM);
    gateup_bf_kernel<false><<<704, 256, 0, stream>>>(
        Xb, R1a, R1b, shb, nullptr, nullptr, nullptr, ISDIM, 44);
    transpose_cvt_kernel<<<dim3(HDIM / 64, ISDIM / 64, 1), 256, 0, stream>>>(sw_down, R1a, ISDIM, HDIM);
    down_bf_kernel<false, 2><<<512, 256, 0, stream>>>(
        shb, R1a, out, nullptr, sg, nullptr, nullptr, ISDIM, (ISDIM / 64) / 2);
    transpose_cvt_kernel<<<dim3(IDIM / 64, HDIM / 64, NEXP), 256, 0, stream>>>(w_gate, R1a, HDIM, IDIM);
    transpose_cvt_kernel<<<dim3(IDIM / 64, HDIM / 64, NEXP), 256, 0, stream>>>(w_up,   R1b, HDIM, IDIM);
    gateup_bf_kernel<true><<<1408, 256, 0, stream>>>(
        Xb, R1a, R1b, hb, list, offs, cnt, IDIM, 11);
    transpose_cvt_kernel<<<dim3(HDIM / 64, IDIM / 64, NEXP), 256, 0, stream>>>(w_down, R1a, IDIM, HDIM);
    down_bf_kernel<true, 1><<<2048, 256, 0, stream>>>(
        hb, R1a, out, list, wl, offs, cnt, IDIM, IDIM / 64);
  }
}

// Round 12
// 587.700 us; speedup vs baseline: 1.0933x; 1.0933x over previous
//
#include <hip/hip_runtime.h>
#include <hip/hip_bf16.h>
#include <stdint.h>

// Qwen3.5 MoE block: router top-2 sparse dispatch + shared expert (SwiGLU), bf16 MFMA.
// B=2,S=1024 -> TOK=2048 tokens. H=2048, I=1408, IS=5632, E=8, K=2. Output f32.
// Round 12: down reverted to r10 256x128 geometry + 3-buffer prefetch-distance-2
// single-barrier pipeline (vmcnt(3)+bar; STAGE(t+2); COMPUTE(t)). Gateup = r10.
#define TOK   2048
#define HDIM  2048
#define IDIM  1408
#define ISDIM 5632
#define NEXP  8

typedef float  f32x4  __attribute__((ext_vector_type(4)));
typedef short  bf16x8 __attribute__((ext_vector_type(8)));

__device__ __forceinline__ unsigned short f2b(float f) {
  union { float f; uint32_t u; } v; v.f = f;
  return (unsigned short)((v.u + 0x7fffu + ((v.u >> 16) & 1u)) >> 16); // RNE
}

// async global->LDS DMA, 16 B per lane: LDS dest wave-uniform base + lane*16.
__device__ __forceinline__ void async16(void* lds, const void* g) {
  __builtin_amdgcn_global_load_lds(
      (const __attribute__((address_space(1))) unsigned int*)g,
      (__attribute__((address_space(3))) unsigned int*)lds, 16, 0, 0);
}

// counted-vmcnt + raw barrier (no lgkm/vm drain); "memory" clobber pins LDS/VMEM ops.
#define VWAIT_BAR(N) asm volatile("s_waitcnt vmcnt(" #N ")\n\ts_barrier" ::: "memory")
#define VBAR()       asm volatile("s_barrier" ::: "memory")

// ---------------- router ----------------
__global__ __launch_bounds__(256) void router_kernel(
    const float* __restrict__ X, const float* __restrict__ GW,
    const float* __restrict__ SGW, int* __restrict__ cnt,
    int* __restrict__ tok_e, float* __restrict__ tok_w, float* __restrict__ sg)
{
  const int tkn = blockIdx.x, t = threadIdx.x;
  const float* xr = X + (size_t)tkn * HDIM;
  float a[NEXP + 1];
  #pragma unroll
  for (int e = 0; e <= NEXP; ++e) a[e] = 0.f;
  for (int h = t; h < HDIM; h += 256) {
    const float xv = xr[h];
    #pragma unroll
    for (int e = 0; e < NEXP; ++e) a[e] += xv * GW[e * HDIM + h];
    a[NEXP] += xv * SGW[h];
  }
  #pragma unroll
  for (int off = 32; off > 0; off >>= 1) {
    #pragma unroll
    for (int e = 0; e <= NEXP; ++e) a[e] += __shfl_down(a[e], off);
  }
  __shared__ float red[4][NEXP + 1];
  if ((t & 63) == 0) {
    #pragma unroll
    for (int e = 0; e <= NEXP; ++e) red[t >> 6][e] = a[e];
  }
  __syncthreads();
  if (t == 0) {
    float l[NEXP + 1];
    #pragma unroll
    for (int e = 0; e <= NEXP; ++e) l[e] = red[0][e] + red[1][e] + red[2][e] + red[3][e];
    int i1 = 0;
    #pragma unroll
    for (int e = 1; e < NEXP; ++e) if (l[e] > l[i1]) i1 = e;
    int i2 = (i1 == 0) ? 1 : 0;
    #pragma unroll
    for (int e = 0; e < NEXP; ++e) if (e != i1 && e != i2 && l[e] > l[i2]) i2 = e;
    const float w1 = 1.f / (1.f + __expf(l[i2] - l[i1]));   // softmax+top2+renorm == sigmoid(diff)
    tok_e[tkn * 2 + 0] = i1; tok_e[tkn * 2 + 1] = i2;
    tok_w[tkn * 2 + 0] = w1; tok_w[tkn * 2 + 1] = 1.f - w1;
    atomicAdd(&cnt[i1], 1); atomicAdd(&cnt[i2], 1);
    sg[tkn] = 1.f / (1.f + __expf(-l[NEXP]));
  }
}

__global__ void scan_kernel(const int* __restrict__ cnt, int* __restrict__ offs) {
  if (threadIdx.x == 0) {
    int r = 0;
    for (int e = 0; e < NEXP; ++e) { offs[e] = r; r += cnt[e]; }
  }
}

__global__ __launch_bounds__(256) void build_kernel(
    const int* __restrict__ tok_e, const float* __restrict__ tok_w,
    const int* __restrict__ offs, int* __restrict__ cur,
    int* __restrict__ list, float* __restrict__ wl)
{
  const int tkn = blockIdx.x * 256 + threadIdx.x;
  if (tkn >= TOK) return;
  #pragma unroll
  for (int k = 0; k < 2; ++k) {
    const int e = tok_e[tkn * 2 + k];
    const int pos = atomicAdd(&cur[e], 1);
    const int slot = offs[e] + pos;
    list[slot] = tkn;
    wl[slot] = tok_w[tkn * 2 + k];
  }
}

// ---------------- preprocessing ----------------
__global__ __launch_bounds__(256) void cvt_kernel(
    const float* __restrict__ src, unsigned short* __restrict__ dst, int n4)
{
  const int i = blockIdx.x * 512 + threadIdx.x;
  #pragma unroll
  for (int p = 0; p < 2; ++p) {
    const int j = i + p * 256;
    if (j < n4) {
      const float4 v = ((const float4*)src)[j];
      ushort4 b; b.x = f2b(v.x); b.y = f2b(v.y); b.z = f2b(v.z); b.w = f2b(v.w);
      ((ushort4*)dst)[j] = b;
    }
  }
}

// f32 [R][C] -> bf16 [C][R], per-z matrix. grid (C/64, R/64, nmat)
__global__ __launch_bounds__(256) void transpose_cvt_kernel(
    const float* __restrict__ src, unsigned short* __restrict__ dst,
    const int R, const int C)
{
  __shared__ unsigned short tile[64][72];
  const size_t mat = (size_t)blockIdx.z * R * C;
  const int c0 = blockIdx.x * 64, r0 = blockIdx.y * 64;
  const int t = threadIdx.x;
  const int rr = t >> 4, cc = (t & 15) * 4;
  #pragma unroll
  for (int p = 0; p < 4; ++p) {
    const int r = rr + p * 16;
    const float4 v = *(const float4*)(src + mat + (size_t)(r0 + r) * C + c0 + cc);
    tile[cc + 0][r] = f2b(v.x);
    tile[cc + 1][r] = f2b(v.y);
    tile[cc + 2][r] = f2b(v.z);
    tile[cc + 3][r] = f2b(v.w);
  }
  __syncthreads();
  #pragma unroll
  for (int p = 0; p < 2; ++p) {
    const int id = p * 256 + t;
    const int c = id >> 3, q = id & 7;
    const uint4 v = *(const uint4*)&tile[c][q * 8];
    *(uint4*)(dst + mat + (size_t)(c0 + c) * R + r0 + q * 8) = v;
  }
}

// ---------------- FUSED gateup: 256x128 tile, 8 waves, BK=32, counted-vmcnt dbuf ----------------
// (unchanged from round 10: 206 us, MfmaUtil 33%)
__global__ __launch_bounds__(512) void gateup_fused_kernel(
    const unsigned short* __restrict__ Xb,
    const unsigned short* __restrict__ Wshg, const unsigned short* __restrict__ Wshu,
    const unsigned short* __restrict__ Wexg, const unsigned short* __restrict__ Wexu,
    unsigned short* __restrict__ shb, unsigned short* __restrict__ hb,
    const int* __restrict__ list, const int* __restrict__ offs, const int* __restrict__ cnt)
{
  __shared__ char smem[65536];

  const int xcd = blockIdx.x & 7;
  const int local = blockIdx.x >> 3;
  const int c = xcd + 8 * (local >> 3);
  const int mt = local & 7;
  if (c >= 132) return;
  const int t = threadIdx.x;

  int rowbase, mcnt, n0, N, gather;
  const unsigned short *Wg, *Wu;
  unsigned short* Cout;
  if (c < 44) {
    N = ISDIM; n0 = c * 128; rowbase = mt * 256; mcnt = 256; gather = 0;
    Wg = Wshg; Wu = Wshu; Cout = shb;
  } else {
    const int cE = c - 44;
    const int e = cE / 11, n = cE % 11;
    mcnt = cnt[e] - mt * 256;
    if (mcnt <= 0) return;
    N = IDIM; n0 = n * 128; rowbase = offs[e] + mt * 256; gather = 1;
    Wg = Wexg + (size_t)e * IDIM * HDIM;
    Wu = Wexu + (size_t)e * IDIM * HDIM;
    Cout = hb;
  }

  const int wid = t >> 6, lane = t & 63;
  const int wm = wid >> 1, wn = wid & 1;
  const int lcol = lane & 15, lk = lane >> 4;

  f32x4 accg[4][4], accu[4][4];
  #pragma unroll
  for (int i = 0; i < 4; ++i)
    #pragma unroll
    for (int j = 0; j < 4; ++j) { accg[i][j] = {0.f,0.f,0.f,0.f}; accu[i][j] = {0.f,0.f,0.f,0.f}; }

  int arow[2], akoff[2];
  #pragma unroll
  for (int p = 0; p < 2; ++p) {
    const int s = p * 512 + t;
    const int m = s >> 2;
    akoff[p] = (((s & 3) ^ ((m >> 1) & 3)) << 3);
    arow[p] = gather ? list[rowbase + m] : (rowbase + m);   // list zero-padded (4608)
  }
  const int albase0 = (t & 448) * 16;
  const int albase1 = (512 + (t & 448)) * 16;
  const int bmrow = n0 + (t >> 2);
  const int bkoff = (((t & 3) ^ (((t >> 2) >> 1) & 3)) << 3);
  const int blbase = (t & 448) * 16;

#define STAGE_GU(BUF, K0) do {                                                    \
    async16(smem + (BUF) + albase0,        Xb + (size_t)arow[0] * HDIM + (K0) + akoff[0]); \
    async16(smem + (BUF) + albase1,        Xb + (size_t)arow[1] * HDIM + (K0) + akoff[1]); \
    async16(smem + (BUF) + 16384 + blbase, Wg + (size_t)bmrow * HDIM + (K0) + bkoff); \
    async16(smem + (BUF) + 24576 + blbase, Wu + (size_t)bmrow * HDIM + (K0) + bkoff); \
  } while (0)

#define COMPUTE_GU(BUF) do {                                                      \
    bf16x8 af[4], bg[4], bu[4];                                                   \
    _Pragma("unroll")                                                             \
    for (int fm = 0; fm < 4; ++fm) {                                              \
      const int m = wm * 64 + fm * 16 + lcol;                                     \
      af[fm] = *(const bf16x8*)(smem + (BUF) + m * 64 + (((lk ^ ((m >> 1) & 3)) & 3) << 4)); \
    }                                                                             \
    _Pragma("unroll")                                                             \
    for (int fn = 0; fn < 4; ++fn) {                                              \
      const int n = wn * 64 + fn * 16 + lcol;                                     \
      const int ra = n * 64 + (((lk ^ ((n >> 1) & 3)) & 3) << 4);                 \
      bg[fn] = *(const bf16x8*)(smem + (BUF) + 16384 + ra);                       \
      bu[fn] = *(const bf16x8*)(smem + (BUF) + 24576 + ra);                       \
    }                                                                             \
    _Pragma("unroll")                                                             \
    for (int fm = 0; fm < 4; ++fm)                                                \
      _Pragma("unroll")                                                           \
      for (int fn = 0; fn < 4; ++fn) {                                            \
        accg[fm][fn] = __builtin_amdgcn_mfma_f32_16x16x32_bf16(af[fm], bg[fn], accg[fm][fn], 0, 0, 0); \
        accu[fm][fn] = __builtin_amdgcn_mfma_f32_16x16x32_bf16(af[fm], bu[fn], accu[fm][fn], 0, 0, 0); \
      } } while (0)

  STAGE_GU(0, 0);
  for (int it = 0; it < 31; ++it) {
    STAGE_GU(32768, (2 * it + 1) * 32);
    VWAIT_BAR(4);
    COMPUTE_GU(0);
    VBAR();
    STAGE_GU(0, (2 * it + 2) * 32);
    VWAIT_BAR(4);
    COMPUTE_GU(32768);
    VBAR();
  }
  STAGE_GU(32768, 63 * 32);
  VWAIT_BAR(4);
  COMPUTE_GU(0);
  VBAR();
  VWAIT_BAR(0);
  COMPUTE_GU(32768);
#undef STAGE_GU
#undef COMPUTE_GU

  #pragma unroll
  for (int fm = 0; fm < 4; ++fm) {
    #pragma unroll
    for (int fn = 0; fn < 4; ++fn) {
      const int col = n0 + wn * 64 + fn * 16 + lcol;
      #pragma unroll
      for (int r = 0; r < 4; ++r) {
        const int lrow = wm * 64 + fm * 16 + lk * 4 + r;
        if (lrow < mcnt) {
          const float gv = accg[fm][fn][r];
          const float uv = accu[fm][fn][r];
          const float hv = gv * uv / (1.f + __expf(-gv));
          Cout[(size_t)(rowbase + lrow) * N + col] = f2b(hv);
        }
      }
    }
  }
}

// ---------------- FUSED down: 256x128, 8 waves, BK=32, 3-buffer depth-2 pipeline ----------------
// LDS/buffer: A 256x32 (16K) + B 128x32 (8K) = 24K; x3 = 72K -> 2 blk/CU.
// Per step: vmcnt(3)+s_barrier (STAGE(t) landed everywhere, STAGE(t+1) in flight);
// STAGE(t+2); COMPUTE(t). One barrier per K-step, 2 compute phases of load latency cover.
// columns: 64 shared (16 pn x 4 ksp, 44 steps) + 128 expert (8e x 16pn, 44 steps).
// grid 1536 = 8 xcd x 24 colslots x 8 mt. All atomicAdd into zeroed out.
__global__ __launch_bounds__(512) void down_fused_kernel(
    const unsigned short* __restrict__ shb, const unsigned short* __restrict__ hb,
    const unsigned short* __restrict__ WdshT, const unsigned short* __restrict__ WdexT,
    float* __restrict__ out,
    const int* __restrict__ list, const float* __restrict__ wl, const float* __restrict__ sg,
    const int* __restrict__ offs, const int* __restrict__ cnt)
{
  __shared__ char smem[73728];   // 3 x 24K

  const int xcd = blockIdx.x & 7;
  const int local = blockIdx.x >> 3;          // 0..191
  const int c = xcd + 8 * (local >> 3);       // 0..191
  const int mt = local & 7;
  const int t = threadIdx.x;

  int rowbase, mcnt, n0, K, kbeg, em;
  const unsigned short *Ap, *Bp;
  if (c < 64) {                // shared, splitK=4 (44 steps each)
    const int pn = c & 15, ksp = c >> 4;
    rowbase = mt * 256; mcnt = 256; n0 = pn * 128;
    K = ISDIM; kbeg = ksp * 44; em = 0;
    Ap = shb; Bp = WdshT;
  } else {                     // expert (44 steps)
    const int cE = c - 64;
    const int e = cE >> 4, n = cE & 15;
    mcnt = cnt[e] - mt * 256;
    if (mcnt <= 0) return;
    rowbase = offs[e] + mt * 256; n0 = n * 128;
    K = IDIM; kbeg = 0; em = 1;
    Ap = hb; Bp = WdexT + (size_t)e * HDIM * IDIM;
  }

  const int wid = t >> 6, lane = t & 63;
  const int wm = wid >> 1, wn = wid & 1;      // wave: 64 rows x 64 cols
  const int lcol = lane & 15, lk = lane >> 4;

  f32x4 acc[4][4];
  #pragma unroll
  for (int i = 0; i < 4; ++i)
    #pragma unroll
    for (int j = 0; j < 4; ++j) acc[i][j] = {0.f,0.f,0.f,0.f};

  // A staging: 2 passes (256 rows x 4 granules); B staging: 1 pass (128 rows x 4 granules)
  int amrow[2], akoff[2];
  #pragma unroll
  for (int p = 0; p < 2; ++p) {
    const int s = p * 512 + t;
    const int m = s >> 2;
    akoff[p] = (((s & 3) ^ ((m >> 1) & 3)) << 3);
    int rw = rowbase + m;
    if (em && rw > 4223) rw = 4223;    // clamp: hb has 4224 row slots
    amrow[p] = rw;
  }
  const int albase0 = (t & 448) * 16;
  const int albase1 = (512 + (t & 448)) * 16;
  const int bmrow = n0 + (t >> 2);
  const int bkoff = (((t & 3) ^ (((t >> 2) >> 1) & 3)) << 3);
  const int blbase = (t & 448) * 16;

#define STAGE_D(BUF, K0) do {                                                     \
    async16(smem + (BUF) + albase0,        Ap + (size_t)amrow[0] * K + (K0) + akoff[0]); \
    async16(smem + (BUF) + albase1,        Ap + (size_t)amrow[1] * K + (K0) + akoff[1]); \
    async16(smem + (BUF) + 16384 + blbase, Bp + (size_t)bmrow * K + (K0) + bkoff); \
  } while (0)

#define COMPUTE_D(BUF) do {                                                       \
    bf16x8 af[4], bfr[4];                                                         \
    _Pragma("unroll")                                                             \
    for (int fm = 0; fm < 4; ++fm) {                                              \
      const int m = wm * 64 + fm * 16 + lcol;                                     \
      af[fm] = *(const bf16x8*)(smem + (BUF) + m * 64 + (((lk ^ ((m >> 1) & 3)) & 3) << 4)); \
    }                                                                             \
    _Pragma("unroll")                                                             \
    for (int fn = 0; fn < 4; ++fn) {                                              \
      const int n = wn * 64 + fn * 16 + lcol;                                     \
      bfr[fn] = *(const bf16x8*)(smem + (BUF) + 16384 + n * 64 + (((lk ^ ((n >> 1) & 3)) & 3) << 4)); \
    }                                                                             \
    _Pragma("unroll")                                                             \
    for (int fm = 0; fm < 4; ++fm)                                                \
      _Pragma("unroll")                                                           \
      for (int fn = 0; fn < 4; ++fn)                                              \
        acc[fm][fn] = __builtin_amdgcn_mfma_f32_16x16x32_bf16(af[fm], bfr[fn], acc[fm][fn], 0, 0, 0); \
  } while (0)

  // 44 steps, 3 buffers at 0 / 24576 / 49152. Prologue stages 0,1; 14 groups of 3
  // stage idx 2..43 and compute 0..41; tail computes 42,43.
  const int kb = kbeg * 32;
  STAGE_D(0,     kb);
  STAGE_D(24576, kb + 32);
  for (int j = 0; j < 14; ++j) {
    const int k2 = kb + (3 * j + 2) * 32;
    VWAIT_BAR(3);
    STAGE_D(49152, k2);
    COMPUTE_D(0);
    VWAIT_BAR(3);
    STAGE_D(0, k2 + 32);
    COMPUTE_D(24576);
    VWAIT_BAR(3);
    STAGE_D(24576, k2 + 64);
    COMPUTE_D(49152);
  }
  VWAIT_BAR(3);
  COMPUTE_D(0);        // step 42 -> buf 42%3 = 0
  VWAIT_BAR(0);
  COMPUTE_D(24576);    // step 43 -> buf 1
#undef STAGE_D
#undef COMPUTE_D

  #pragma unroll
  for (int fm = 0; fm < 4; ++fm) {
    #pragma unroll
    for (int fn = 0; fn < 4; ++fn) {
      const int col = n0 + wn * 64 + fn * 16 + lcol;
      #pragma unroll
      for (int r = 0; r < 4; ++r) {
        const int lrow = wm * 64 + fm * 16 + lk * 4 + r;
        if (lrow < mcnt) {
          const float v = acc[fm][fn][r];
          const int sl = rowbase + lrow;
          const int orow = em ? list[sl] : sl;
          const float sc = em ? wl[sl] : sg[sl];
          atomicAdd(out + (size_t)orow * HDIM + col, sc * v);
        }
      }
    }
  }
}

// ================= round-4 path (ws in [136MB, 182MB)) =================
template<bool GATHER>
__global__ __launch_bounds__(256) void gateup_bf_kernel(
    const unsigned short* __restrict__ Xb,
    const unsigned short* __restrict__ WgT, const unsigned short* __restrict__ WuT,
    unsigned short* __restrict__ Cout,
    const int* __restrict__ list, const int* __restrict__ offs,
    const int* __restrict__ cnt, const int N, const int NT)
{
  __shared__ char smem[49152];
  char* sA  = smem;
  char* sBg = smem + 16384;
  char* sBu = smem + 32768;
  int wg = blockIdx.x;
  wg = (wg & 7) * (gridDim.x >> 3) + (wg >> 3);
  const int mt = wg & 15;
  const int pn = wg >> 4;
  const int t = threadIdx.x;
  int rowbase, mcnt, n0;
  const unsigned short *Wg, *Wu;
  if (GATHER) {
    const int e = pn / NT, n = pn % NT;
    mcnt = cnt[e] - mt * 128;
    if (mcnt <= 0) return;
    rowbase = offs[e] + mt * 128;
    n0 = n * 128;
    Wg = WgT + (size_t)e * N * HDIM;
    Wu = WuT + (size_t)e * N * HDIM;
  } else {
    rowbase = mt * 128; mcnt = 128; n0 = pn * 128;
    Wg = WgT; Wu = WuT;
  }
  const int w = t >> 6, lane = t & 63;
  const int wr = w >> 1, wc = w & 1;
  const int lcol = lane & 15, lk = lane >> 4;
  f32x4 accg[4][4], accu[4][4];
  #pragma unroll
  for (int i = 0; i < 4; ++i)
    #pragma unroll
    for (int j = 0; j < 4; ++j) { accg[i][j] = {0.f,0.f,0.f,0.f}; accu[i][j] = {0.f,0.f,0.f,0.f}; }
  int arow[4], bm[4], koff[4];
  #pragma unroll
  for (int p = 0; p < 4; ++p) {
    const int s = p * 256 + t;
    const int m = s >> 3;
    bm[p] = m;
    koff[p] = ((s & 7) ^ (m & 7)) << 3;
    arow[p] = GATHER ? list[rowbase + m] : (rowbase + m);
  }
  const int KSTEPS = HDIM / 64;
  for (int kt = 0; kt < KSTEPS; ++kt) {
    const int k0 = kt * 64;
    if (kt) __syncthreads();
    #pragma unroll
    for (int p = 0; p < 4; ++p) {
      const int lb = (p * 256 + (t & 192)) * 16;
      async16(sA  + lb, Xb + (size_t)arow[p] * HDIM + k0 + koff[p]);
      async16(sBg + lb, Wg + (size_t)(n0 + bm[p]) * HDIM + k0 + koff[p]);
      async16(sBu + lb, Wu + (size_t)(n0 + bm[p]) * HDIM + k0 + koff[p]);
    }
    __syncthreads();
    #pragma unroll
    for (int ks = 0; ks < 2; ++ks) {
      bf16x8 af[4], bg[4], bu[4];
      #pragma unroll
      for (int fm = 0; fm < 4; ++fm) {
        const int m = wr * 64 + fm * 16 + lcol;
        af[fm] = *(const bf16x8*)(sA + m * 128 + (((ks * 4 + lk) ^ (m & 7)) << 4));
      }
      #pragma unroll
      for (int fn = 0; fn < 4; ++fn) {
        const int n = wc * 64 + fn * 16 + lcol;
        const int ra = n * 128 + (((ks * 4 + lk) ^ (n & 7)) << 4);
        bg[fn] = *(const bf16x8*)(sBg + ra);
        bu[fn] = *(const bf16x8*)(sBu + ra);
      }
      #pragma unroll
      for (int fm = 0; fm < 4; ++fm)
        #pragma unroll
        for (int fn = 0; fn < 4; ++fn) {
          accg[fm][fn] = __builtin_amdgcn_mfma_f32_16x16x32_bf16(af[fm], bg[fn], accg[fm][fn], 0, 0, 0);
          accu[fm][fn] = __builtin_amdgcn_mfma_f32_16x16x32_bf16(af[fm], bu[fn], accu[fm][fn], 0, 0, 0);
        }
    }
  }
  #pragma unroll
  for (int fm = 0; fm < 4; ++fm) {
    #pragma unroll
    for (int fn = 0; fn < 4; ++fn) {
      const int col = n0 + wc * 64 + fn * 16 + lcol;
      #pragma unroll
      for (int r = 0; r < 4; ++r) {
        const int lrow = wr * 64 + fm * 16 + lk * 4 + r;
        if (lrow < mcnt) {
          const float gv = accg[fm][fn][r];
          const float uv = accu[fm][fn][r];
          Cout[(size_t)(rowbase + lrow) * N + col] = f2b(gv * uv / (1.f + __expf(-gv)));
        }
      }
    }
  }
}

template<bool EXPERT, int KSPLIT>
__global__ __launch_bounds__(256) void down_bf_kernel(
    const unsigned short* __restrict__ Abuf,
    const unsigned short* __restrict__ BT,
    float* __restrict__ out,
    const int* __restrict__ list, const float* __restrict__ wl,
    const int* __restrict__ offs, const int* __restrict__ cnt,
    const int K, const int ktps)
{
  __shared__ char smem[32768];
  char* sA = smem;
  char* sB = smem + 16384;
  int wg = blockIdx.x;
  wg = (wg & 7) * (gridDim.x >> 3) + (wg >> 3);
  const int ksp = wg % KSPLIT;
  const int mt  = (wg / KSPLIT) & 15;
  const int pn  = wg / (KSPLIT * 16);
  const int t = threadIdx.x;
  int rowbase, mcnt, n0;
  const unsigned short* Bm;
  if (EXPERT) {
    const int e = pn >> 4, n = pn & 15;
    mcnt = cnt[e] - mt * 128;
    if (mcnt <= 0) return;
    rowbase = offs[e] + mt * 128;
    n0 = n * 128;
    Bm = BT + (size_t)e * HDIM * K;
  } else {
    rowbase = mt * 128; mcnt = 128; n0 = pn * 128;
    Bm = BT;
  }
  const int w = t >> 6, lane = t & 63;
  const int wr = w >> 1, wc = w & 1;
  const int lcol = lane & 15, lk = lane >> 4;
  f32x4 acc[4][4];
  #pragma unroll
  for (int i = 0; i < 4; ++i)
    #pragma unroll
    for (int j = 0; j < 4; ++j) acc[i][j] = {0.f,0.f,0.f,0.f};
  int bm[4], koff[4];
  #pragma unroll
  for (int p = 0; p < 4; ++p) {
    const int s = p * 256 + t;
    const int m = s >> 3;
    bm[p] = m;
    koff[p] = ((s & 7) ^ (m & 7)) << 3;
  }
  const int kbeg = ksp * ktps, kend = kbeg + ktps;
  for (int kt = kbeg; kt < kend; ++kt) {
    const int k0 = kt * 64;
    if (kt != kbeg) __syncthreads();
    #pragma unroll
    for (int p = 0; p < 4; ++p) {
      const int lb = (p * 256 + (t & 192)) * 16;
      async16(sA + lb, Abuf + (size_t)(rowbase + bm[p]) * K + k0 + koff[p]);
      async16(sB + lb, Bm + (size_t)(n0 + bm[p]) * K + k0 + koff[p]);
    }
    __syncthreads();
    #pragma unroll
    for (int ks = 0; ks < 2; ++ks) {
      bf16x8 af[4], bfr[4];
      #pragma unroll
      for (int fm = 0; fm < 4; ++fm) {
        const int m = wr * 64 + fm * 16 + lcol;
        af[fm] = *(const bf16x8*)(sA + m * 128 + (((ks * 4 + lk) ^ (m & 7)) << 4));
      }
      #pragma unroll
      for (int fn = 0; fn < 4; ++fn) {
        const int n = wc * 64 + fn * 16 + lcol;
        bfr[fn] = *(const bf16x8*)(sB + n * 128 + (((ks * 4 + lk) ^ (n & 7)) << 4));
      }
      #pragma unroll
      for (int fm = 0; fm < 4; ++fm)
        #pragma unroll
        for (int fn = 0; fn < 4; ++fn)
          acc[fm][fn] = __builtin_amdgcn_mfma_f32_16x16x32_bf16(af[fm], bfr[fn], acc[fm][fn], 0, 0, 0);
    }
  }
  #pragma unroll
  for (int fm = 0; fm < 4; ++fm) {
    #pragma unroll
    for (int fn = 0; fn < 4; ++fn) {
      const int col = n0 + wc * 64 + fn * 16 + lcol;
      #pragma unroll
      for (int r = 0; r < 4; ++r) {
        const int lrow = wr * 64 + fm * 16 + lk * 4 + r;
        if (lrow < mcnt) {
          const float v = acc[fm][fn][r];
          if (EXPERT) {
            const int slot = rowbase + lrow;
            atomicAdd(out + (size_t)list[slot] * HDIM + col, wl[slot] * v);
          } else {
            const int row = rowbase + lrow;
            atomicAdd(out + (size_t)row * HDIM + col, wl[row] * v);
          }
        }
      }
    }
  }
}

extern "C" void kernel_launch(void* const* d_in, const int* in_sizes, int n_in,
                              void* d_out, int out_size, void* d_ws, size_t ws_size,
                              hipStream_t stream)
{
  const float* x       = (const float*)d_in[0];
  const float* gate_w  = (const float*)d_in[1];
  const float* w_gate  = (const float*)d_in[2];
  const float* w_up    = (const float*)d_in[3];
  const float* w_down  = (const float*)d_in[4];
  const float* sw_gate = (const float*)d_in[5];
  const float* sw_up   = (const float*)d_in[6];
  const float* sw_down = (const float*)d_in[7];
  const float* sgw     = (const float*)d_in[8];

  float* out = (float*)d_out;   // f32 [TOK][H]; pure accumulator (zeroed)
  char* ws = (char*)d_ws;

  const size_t NEED_FUSED = 182000000;
  const size_t NEED_R4    = 136000000;

  if (ws_size >= NEED_FUSED) {
    unsigned short* Xb  = (unsigned short*)ws;                      //   8,388,608
    unsigned short* W1  = (unsigned short*)(ws + 8388608);          //  23,068,672 shG^T / later shDown^T
    unsigned short* W2  = (unsigned short*)(ws + 31457280);         //  23,068,672 shU^T
    unsigned short* W3  = (unsigned short*)(ws + 54525952);         //  46,137,344 exG^T / later exDown^T
    unsigned short* W4  = (unsigned short*)(ws + 100663296);        //  46,137,344 exU^T
    unsigned short* shb = (unsigned short*)(ws + 146800640);        //  23,068,672
    unsigned short* hb  = (unsigned short*)(ws + 169869312);        //  11,894,784
    char* meta = ws + 181764096;
    int*   cnt   = (int*)(meta);
    int*   cur   = (int*)(meta + 256);
    int*   offs  = (int*)(meta + 512);
    int*   list  = (int*)(meta + 768);                 // 4608 ints (zero-padded)
    float* wl    = (float*)(meta + 768 + 18432);       // 4608 floats (zero-padded)
    int*   tok_e = (int*)(meta + 768 + 2 * 18432);
    float* tok_w = (float*)(meta + 768 + 2 * 18432 + 16384);
    float* sg    = (float*)(meta + 768 + 2 * 18432 + 32768);

    hipMemsetAsync(meta, 0, 768 + 2 * 18432, stream);
    hipMemsetAsync(out, 0, (size_t)TOK * HDIM * 4, stream);

    cvt_kernel<<<TOK * HDIM / 4 / 512, 256, 0, stream>>>(x, Xb, TOK * HDIM / 4);
    router_kernel<<<TOK, 256, 0, stream>>>(x, gate_w, sgw, cnt, tok_e, tok_w, sg);
    scan_kernel<<<1, 64, 0, stream>>>(cnt, offs);
    build_kernel<<<8, 256, 0, stream>>>(tok_e, tok_w, offs, cur, list, wl);

    transpose_cvt_kernel<<<dim3(ISDIM / 64, HDIM / 64, 1), 256, 0, stream>>>(sw_gate, W1, HDIM, ISDIM);
    transpose_cvt_kernel<<<dim3(ISDIM / 64, HDIM / 64, 1), 256, 0, stream>>>(sw_up,   W2, HDIM, ISDIM);
    transpose_cvt_kernel<<<dim3(IDIM / 64, HDIM / 64, NEXP), 256, 0, stream>>>(w_gate, W3, HDIM, IDIM);
    transpose_cvt_kernel<<<dim3(IDIM / 64, HDIM / 64, NEXP), 256, 0, stream>>>(w_up,   W4, HDIM, IDIM);

    // grid 1088 = 8 xcd x 17 col-slots x 8 mt (cols >=132 return), 512 threads
    gateup_fused_kernel<<<1088, 512, 0, stream>>>(Xb, W1, W2, W3, W4, shb, hb, list, offs, cnt);

    transpose_cvt_kernel<<<dim3(HDIM / 64, ISDIM / 64, 1), 256, 0, stream>>>(sw_down, W1, ISDIM, HDIM);
    transpose_cvt_kernel<<<dim3(HDIM / 64, IDIM / 64, NEXP), 256, 0, stream>>>(w_down, W3, IDIM, HDIM);

    // grid 1536 = 8 xcd x 24 col-slots x 8 mt, 512 threads
    down_fused_kernel<<<1536, 512, 0, stream>>>(shb, hb, W1, W3, out, list, wl, sg, offs, cnt);
  } else if (ws_size >= NEED_R4) {
    unsigned short* Xb   = (unsigned short*)ws;
    unsigned short* R1a  = (unsigned short*)(ws + 8388608);
    unsigned short* R1b  = (unsigned short*)(ws + 54525952);
    unsigned short* shb  = (unsigned short*)(ws + 100663296);
    unsigned short* hb   = (unsigned short*)(ws + 123731968);
    char* meta = ws + 135626752;
    int*   cnt   = (int*)(meta);
    int*   cur   = (int*)(meta + 256);
    int*   offs  = (int*)(meta + 512);
    int*   list  = (int*)(meta + 768);
    float* wl    = (float*)(meta + 768 + 17152);
    int*   tok_e = (int*)(meta + 768 + 2 * 17152);
    float* tok_w = (float*)(meta + 768 + 2 * 17152 + 16384);
    float* sg    = (float*)(meta + 768 + 2 * 17152 + 32768);

    hipMemsetAsync(meta, 0, 768 + 2 * 17152, stream);
    hipMemsetAsync(out, 0, (size_t)TOK * HDIM * 4, stream);

    cvt_kernel<<<TOK * HDIM / 4 / 512, 256, 0, stream>>>(x, Xb, TOK * HDIM / 4);
    router_kernel<<<TOK, 256, 0, stream>>>(x, gate_w, sgw, cnt, tok_e, tok_w, sg);
    scan_kernel<<<1, 64, 0, stream>>>(cnt, offs);
    build_kernel<<<8, 256, 0, stream>>>(tok_e, tok_w, offs, cur, list, wl);

    transpose_cvt_kernel<<<dim3(ISDIM / 64, HDIM / 64, 1), 256, 0, stream>>>(sw_gate, R1a, HDIM, ISDIM);
    transpose_cvt_kernel<<<dim3(ISDIM / 64, HDIM / 64, 1), 256, 0, stream>>>(sw_up,   R1b, HDIM, ISDIM);
    gateup_bf_kernel<false><<<704, 256, 0, stream>>>(
        Xb, R1a, R1b, shb, nullptr, nullptr, nullptr, ISDIM, 44);
    transpose_cvt_kernel<<<dim3(HDIM / 64, ISDIM / 64, 1), 256, 0, stream>>>(sw_down, R1a, ISDIM, HDIM);
    down_bf_kernel<false, 2><<<512, 256, 0, stream>>>(
        shb, R1a, out, nullptr, sg, nullptr, nullptr, ISDIM, (ISDIM / 64) / 2);
    transpose_cvt_kernel<<<dim3(IDIM / 64, HDIM / 64, NEXP), 256, 0, stream>>>(w_gate, R1a, HDIM, IDIM);
    transpose_cvt_kernel<<<dim3(IDIM / 64, HDIM / 64, NEXP), 256, 0, stream>>>(w_up,   R1b, HDIM, IDIM);
    gateup_bf_kernel<true><<<1408, 256, 0, stream>>>(
        Xb, R1a, R1b, hb, list, offs, cnt, IDIM, 11);
    transpose_cvt_kernel<<<dim3(HDIM / 64, IDIM / 64, NEXP), 256, 0, stream>>>(w_down, R1a, IDIM, HDIM);
    down_bf_kernel<true, 1><<<2048, 256, 0, stream>>>(
        hb, R1a, out, list, wl, offs, cnt, IDIM, IDIM / 64);
  }
}

// Round 13
// 587.450 us; speedup vs baseline: 1.0937x; 1.0004x over previous
//
#include <hip/hip_runtime.h>
#include <hip/hip_bf16.h>
#include <stdint.h>

// Qwen3.5 MoE block: router top-2 sparse dispatch + shared expert (SwiGLU), bf16 MFMA.
// B=2,S=1024 -> TOK=2048 tokens. H=2048, I=1408, IS=5632, E=8, K=2. Output f32.
// Round 13: down reverted to round-10 config (2-buffer/48KB/vmcnt(3): best measured).
// Down-weight transposes fused into the gateup dispatch as trailing blocks
// (write fresh W5/W6 -> no race with gateup's W1-W4), hiding ~45us of serial
// HBM work under the compute-bound gateup. Runtime-gated on ws_size.
#define TOK   2048
#define HDIM  2048
#define IDIM  1408
#define ISDIM 5632
#define NEXP  8
#define GU_GEMM_BLOCKS 1088

typedef float  f32x4  __attribute__((ext_vector_type(4)));
typedef short  bf16x8 __attribute__((ext_vector_type(8)));

__device__ __forceinline__ unsigned short f2b(float f) {
  union { float f; uint32_t u; } v; v.f = f;
  return (unsigned short)((v.u + 0x7fffu + ((v.u >> 16) & 1u)) >> 16); // RNE
}

// async global->LDS DMA, 16 B per lane: LDS dest wave-uniform base + lane*16.
__device__ __forceinline__ void async16(void* lds, const void* g) {
  __builtin_amdgcn_global_load_lds(
      (const __attribute__((address_space(1))) unsigned int*)g,
      (__attribute__((address_space(3))) unsigned int*)lds, 16, 0, 0);
}

// counted-vmcnt + raw barrier (no lgkm/vm drain); "memory" clobber pins LDS/VMEM ops.
#define VWAIT_BAR(N) asm volatile("s_waitcnt vmcnt(" #N ")\n\ts_barrier" ::: "memory")
#define VBAR()       asm volatile("s_barrier" ::: "memory")

// ---------------- router ----------------
__global__ __launch_bounds__(256) void router_kernel(
    const float* __restrict__ X, const float* __restrict__ GW,
    const float* __restrict__ SGW, int* __restrict__ cnt,
    int* __restrict__ tok_e, float* __restrict__ tok_w, float* __restrict__ sg)
{
  const int tkn = blockIdx.x, t = threadIdx.x;
  const float* xr = X + (size_t)tkn * HDIM;
  float a[NEXP + 1];
  #pragma unroll
  for (int e = 0; e <= NEXP; ++e) a[e] = 0.f;
  for (int h = t; h < HDIM; h += 256) {
    const float xv = xr[h];
    #pragma unroll
    for (int e = 0; e < NEXP; ++e) a[e] += xv * GW[e * HDIM + h];
    a[NEXP] += xv * SGW[h];
  }
  #pragma unroll
  for (int off = 32; off > 0; off >>= 1) {
    #pragma unroll
    for (int e = 0; e <= NEXP; ++e) a[e] += __shfl_down(a[e], off);
  }
  __shared__ float red[4][NEXP + 1];
  if ((t & 63) == 0) {
    #pragma unroll
    for (int e = 0; e <= NEXP; ++e) red[t >> 6][e] = a[e];
  }
  __syncthreads();
  if (t == 0) {
    float l[NEXP + 1];
    #pragma unroll
    for (int e = 0; e <= NEXP; ++e) l[e] = red[0][e] + red[1][e] + red[2][e] + red[3][e];
    int i1 = 0;
    #pragma unroll
    for (int e = 1; e < NEXP; ++e) if (l[e] > l[i1]) i1 = e;
    int i2 = (i1 == 0) ? 1 : 0;
    #pragma unroll
    for (int e = 0; e < NEXP; ++e) if (e != i1 && e != i2 && l[e] > l[i2]) i2 = e;
    const float w1 = 1.f / (1.f + __expf(l[i2] - l[i1]));   // softmax+top2+renorm == sigmoid(diff)
    tok_e[tkn * 2 + 0] = i1; tok_e[tkn * 2 + 1] = i2;
    tok_w[tkn * 2 + 0] = w1; tok_w[tkn * 2 + 1] = 1.f - w1;
    atomicAdd(&cnt[i1], 1); atomicAdd(&cnt[i2], 1);
    sg[tkn] = 1.f / (1.f + __expf(-l[NEXP]));
  }
}

__global__ void scan_kernel(const int* __restrict__ cnt, int* __restrict__ offs) {
  if (threadIdx.x == 0) {
    int r = 0;
    for (int e = 0; e < NEXP; ++e) { offs[e] = r; r += cnt[e]; }
  }
}

__global__ __launch_bounds__(256) void build_kernel(
    const int* __restrict__ tok_e, const float* __restrict__ tok_w,
    const int* __restrict__ offs, int* __restrict__ cur,
    int* __restrict__ list, float* __restrict__ wl)
{
  const int tkn = blockIdx.x * 256 + threadIdx.x;
  if (tkn >= TOK) return;
  #pragma unroll
  for (int k = 0; k < 2; ++k) {
    const int e = tok_e[tkn * 2 + k];
    const int pos = atomicAdd(&cur[e], 1);
    const int slot = offs[e] + pos;
    list[slot] = tkn;
    wl[slot] = tok_w[tkn * 2 + k];
  }
}

// ---------------- preprocessing ----------------
__global__ __launch_bounds__(256) void cvt_kernel(
    const float* __restrict__ src, unsigned short* __restrict__ dst, int n4)
{
  const int i = blockIdx.x * 512 + threadIdx.x;
  #pragma unroll
  for (int p = 0; p < 2; ++p) {
    const int j = i + p * 256;
    if (j < n4) {
      const float4 v = ((const float4*)src)[j];
      ushort4 b; b.x = f2b(v.x); b.y = f2b(v.y); b.z = f2b(v.z); b.w = f2b(v.w);
      ((ushort4*)dst)[j] = b;
    }
  }
}

// f32 [R][C] -> bf16 [C][R], per-z matrix. grid (C/64, R/64, nmat)
__global__ __launch_bounds__(256) void transpose_cvt_kernel(
    const float* __restrict__ src, unsigned short* __restrict__ dst,
    const int R, const int C)
{
  __shared__ unsigned short tile[64][72];
  const size_t mat = (size_t)blockIdx.z * R * C;
  const int c0 = blockIdx.x * 64, r0 = blockIdx.y * 64;
  const int t = threadIdx.x;
  const int rr = t >> 4, cc = (t & 15) * 4;
  #pragma unroll
  for (int p = 0; p < 4; ++p) {
    const int r = rr + p * 16;
    const float4 v = *(const float4*)(src + mat + (size_t)(r0 + r) * C + c0 + cc);
    tile[cc + 0][r] = f2b(v.x);
    tile[cc + 1][r] = f2b(v.y);
    tile[cc + 2][r] = f2b(v.z);
    tile[cc + 3][r] = f2b(v.w);
  }
  __syncthreads();
  #pragma unroll
  for (int p = 0; p < 2; ++p) {
    const int id = p * 256 + t;
    const int c = id >> 3, q = id & 7;
    const uint4 v = *(const uint4*)&tile[c][q * 8];
    *(uint4*)(dst + mat + (size_t)(c0 + c) * R + r0 + q * 8) = v;
  }
}

// ---------------- FUSED gateup (+optional fused down-weight transposes) ----------------
// GEMM blocks [0, 1088): 256x128 tile, 8 waves, BK=32, counted-vmcnt dbuf (r10).
// Transpose blocks [1088, ...): 2 x (64x64) f32->bf16 transpose tiles per block,
// sw_down -> W5 [HDIM][ISDIM], w_down -> W6 [E][HDIM][IDIM]. Backfill CUs as GEMM drains.
__global__ __launch_bounds__(512) void gateup_fused_kernel(
    const unsigned short* __restrict__ Xb,
    const unsigned short* __restrict__ Wshg, const unsigned short* __restrict__ Wshu,
    const unsigned short* __restrict__ Wexg, const unsigned short* __restrict__ Wexu,
    unsigned short* __restrict__ shb, unsigned short* __restrict__ hb,
    const int* __restrict__ list, const int* __restrict__ offs, const int* __restrict__ cnt,
    const float* __restrict__ swDown, const float* __restrict__ wDown,
    unsigned short* __restrict__ W5, unsigned short* __restrict__ W6)
{
  __shared__ char smem[65536];
  const int t = threadIdx.x;

  if (blockIdx.x >= GU_GEMM_BLOCKS) {
    // ---------- fused transpose blocks ----------
    const int half = t >> 8;          // 0/1: two 64x64 tiles per block
    const int t2 = t & 255;
    int tid2 = (blockIdx.x - GU_GEMM_BLOCKS) * 2 + half;   // 0..8447
    const float* src; unsigned short* dst; int R, cx, ry;
    if (tid2 < 2816) {                // sw_down [ISDIM][HDIM] -> W5 [HDIM][ISDIM]
      src = swDown; dst = W5; R = ISDIM; cx = tid2 & 31; ry = tid2 >> 5;
    } else {                          // w_down e: [IDIM][HDIM] -> W6 e: [HDIM][IDIM]
      tid2 -= 2816;
      const int e = tid2 / 704, rem = tid2 % 704;
      cx = rem & 31; ry = rem >> 5;
      src = wDown + (size_t)e * IDIM * HDIM;
      dst = W6 + (size_t)e * HDIM * IDIM;
      R = IDIM;
    }
    unsigned short (*tile)[72] = (unsigned short(*)[72])(smem + half * 16384);
    const int c0 = cx * 64, r0 = ry * 64;
    const int rr = t2 >> 4, cc = (t2 & 15) * 4;
    #pragma unroll
    for (int p = 0; p < 4; ++p) {
      const int r = rr + p * 16;
      const float4 v = *(const float4*)(src + (size_t)(r0 + r) * HDIM + c0 + cc);
      tile[cc + 0][r] = f2b(v.x);
      tile[cc + 1][r] = f2b(v.y);
      tile[cc + 2][r] = f2b(v.z);
      tile[cc + 3][r] = f2b(v.w);
    }
    __syncthreads();
    #pragma unroll
    for (int p = 0; p < 2; ++p) {
      const int id = p * 256 + t2;
      const int ci = id >> 3, q = id & 7;
      *(uint4*)(dst + (size_t)(c0 + ci) * R + r0 + q * 8) = *(const uint4*)&tile[ci][q * 8];
    }
    return;
  }

  // ---------- GEMM blocks (r10 unchanged) ----------
  const int xcd = blockIdx.x & 7;
  const int local = blockIdx.x >> 3;
  const int c = xcd + 8 * (local >> 3);
  const int mt = local & 7;
  if (c >= 132) return;

  int rowbase, mcnt, n0, N, gather;
  const unsigned short *Wg, *Wu;
  unsigned short* Cout;
  if (c < 44) {
    N = ISDIM; n0 = c * 128; rowbase = mt * 256; mcnt = 256; gather = 0;
    Wg = Wshg; Wu = Wshu; Cout = shb;
  } else {
    const int cE = c - 44;
    const int e = cE / 11, n = cE % 11;
    mcnt = cnt[e] - mt * 256;
    if (mcnt <= 0) return;
    N = IDIM; n0 = n * 128; rowbase = offs[e] + mt * 256; gather = 1;
    Wg = Wexg + (size_t)e * IDIM * HDIM;
    Wu = Wexu + (size_t)e * IDIM * HDIM;
    Cout = hb;
  }

  const int wid = t >> 6, lane = t & 63;
  const int wm = wid >> 1, wn = wid & 1;
  const int lcol = lane & 15, lk = lane >> 4;

  f32x4 accg[4][4], accu[4][4];
  #pragma unroll
  for (int i = 0; i < 4; ++i)
    #pragma unroll
    for (int j = 0; j < 4; ++j) { accg[i][j] = {0.f,0.f,0.f,0.f}; accu[i][j] = {0.f,0.f,0.f,0.f}; }

  int arow[2], akoff[2];
  #pragma unroll
  for (int p = 0; p < 2; ++p) {
    const int s = p * 512 + t;
    const int m = s >> 2;
    akoff[p] = (((s & 3) ^ ((m >> 1) & 3)) << 3);
    arow[p] = gather ? list[rowbase + m] : (rowbase + m);   // list zero-padded (4608)
  }
  const int albase0 = (t & 448) * 16;
  const int albase1 = (512 + (t & 448)) * 16;
  const int bmrow = n0 + (t >> 2);
  const int bkoff = (((t & 3) ^ (((t >> 2) >> 1) & 3)) << 3);
  const int blbase = (t & 448) * 16;

#define STAGE_GU(BUF, K0) do {                                                    \
    async16(smem + (BUF) + albase0,        Xb + (size_t)arow[0] * HDIM + (K0) + akoff[0]); \
    async16(smem + (BUF) + albase1,        Xb + (size_t)arow[1] * HDIM + (K0) + akoff[1]); \
    async16(smem + (BUF) + 16384 + blbase, Wg + (size_t)bmrow * HDIM + (K0) + bkoff); \
    async16(smem + (BUF) + 24576 + blbase, Wu + (size_t)bmrow * HDIM + (K0) + bkoff); \
  } while (0)

#define COMPUTE_GU(BUF) do {                                                      \
    bf16x8 af[4], bg[4], bu[4];                                                   \
    _Pragma("unroll")                                                             \
    for (int fm = 0; fm < 4; ++fm) {                                              \
      const int m = wm * 64 + fm * 16 + lcol;                                     \
      af[fm] = *(const bf16x8*)(smem + (BUF) + m * 64 + (((lk ^ ((m >> 1) & 3)) & 3) << 4)); \
    }                                                                             \
    _Pragma("unroll")                                                             \
    for (int fn = 0; fn < 4; ++fn) {                                              \
      const int n = wn * 64 + fn * 16 + lcol;                                     \
      const int ra = n * 64 + (((lk ^ ((n >> 1) & 3)) & 3) << 4);                 \
      bg[fn] = *(const bf16x8*)(smem + (BUF) + 16384 + ra);                       \
      bu[fn] = *(const bf16x8*)(smem + (BUF) + 24576 + ra);                       \
    }                                                                             \
    _Pragma("unroll")                                                             \
    for (int fm = 0; fm < 4; ++fm)                                                \
      _Pragma("unroll")                                                           \
      for (int fn = 0; fn < 4; ++fn) {                                            \
        accg[fm][fn] = __builtin_amdgcn_mfma_f32_16x16x32_bf16(af[fm], bg[fn], accg[fm][fn], 0, 0, 0); \
        accu[fm][fn] = __builtin_amdgcn_mfma_f32_16x16x32_bf16(af[fm], bu[fn], accu[fm][fn], 0, 0, 0); \
      } } while (0)

  STAGE_GU(0, 0);
  for (int it = 0; it < 31; ++it) {
    STAGE_GU(32768, (2 * it + 1) * 32);
    VWAIT_BAR(4);
    COMPUTE_GU(0);
    VBAR();
    STAGE_GU(0, (2 * it + 2) * 32);
    VWAIT_BAR(4);
    COMPUTE_GU(32768);
    VBAR();
  }
  STAGE_GU(32768, 63 * 32);
  VWAIT_BAR(4);
  COMPUTE_GU(0);
  VBAR();
  VWAIT_BAR(0);
  COMPUTE_GU(32768);
#undef STAGE_GU
#undef COMPUTE_GU

  #pragma unroll
  for (int fm = 0; fm < 4; ++fm) {
    #pragma unroll
    for (int fn = 0; fn < 4; ++fn) {
      const int col = n0 + wn * 64 + fn * 16 + lcol;
      #pragma unroll
      for (int r = 0; r < 4; ++r) {
        const int lrow = wm * 64 + fm * 16 + lk * 4 + r;
        if (lrow < mcnt) {
          const float gv = accg[fm][fn][r];
          const float uv = accu[fm][fn][r];
          const float hv = gv * uv / (1.f + __expf(-gv));
          Cout[(size_t)(rowbase + lrow) * N + col] = f2b(hv);
        }
      }
    }
  }
}

// ---------------- FUSED down: r10 verbatim (256x128, 2-buffer 48KB, vmcnt(3)) ----------------
// columns: 64 shared (16 pn x 4 ksp, 44 steps) + 128 expert (8e x 16pn, 44 steps).
// grid 1536 = 8 xcd x 24 colslots x 8 mt. All atomicAdd into zeroed out.
__global__ __launch_bounds__(512) void down_fused_kernel(
    const unsigned short* __restrict__ shb, const unsigned short* __restrict__ hb,
    const unsigned short* __restrict__ WdshT, const unsigned short* __restrict__ WdexT,
    float* __restrict__ out,
    const int* __restrict__ list, const float* __restrict__ wl, const float* __restrict__ sg,
    const int* __restrict__ offs, const int* __restrict__ cnt)
{
  __shared__ char smem[49152];

  const int xcd = blockIdx.x & 7;
  const int local = blockIdx.x >> 3;
  const int c = xcd + 8 * (local >> 3);   // 0..191
  const int mt = local & 7;
  const int t = threadIdx.x;

  int rowbase, mcnt, n0, K, kbeg, em;
  const unsigned short *Ap, *Bp;
  if (c < 64) {                // shared, splitK=4 (44 steps each)
    const int pn = c & 15, ksp = c >> 4;
    rowbase = mt * 256; mcnt = 256; n0 = pn * 128;
    K = ISDIM; kbeg = ksp * 44; em = 0;
    Ap = shb; Bp = WdshT;
  } else {                     // expert (44 steps)
    const int cE = c - 64;
    const int e = cE >> 4, n = cE & 15;
    mcnt = cnt[e] - mt * 256;
    if (mcnt <= 0) return;
    rowbase = offs[e] + mt * 256; n0 = n * 128;
    K = IDIM; kbeg = 0; em = 1;
    Ap = hb; Bp = WdexT + (size_t)e * HDIM * IDIM;
  }

  const int wid = t >> 6, lane = t & 63;
  const int wm = wid >> 1, wn = wid & 1;
  const int lcol = lane & 15, lk = lane >> 4;

  f32x4 acc[4][4];
  #pragma unroll
  for (int i = 0; i < 4; ++i)
    #pragma unroll
    for (int j = 0; j < 4; ++j) acc[i][j] = {0.f,0.f,0.f,0.f};

  int amrow[2], akoff[2];
  #pragma unroll
  for (int p = 0; p < 2; ++p) {
    const int s = p * 512 + t;
    const int m = s >> 2;
    akoff[p] = (((s & 3) ^ ((m >> 1) & 3)) << 3);
    int rw = rowbase + m;
    if (em && rw > 4223) rw = 4223;    // clamp: hb has 4224 row slots
    amrow[p] = rw;
  }
  const int albase0 = (t & 448) * 16;
  const int albase1 = (512 + (t & 448)) * 16;
  const int bmrow = n0 + (t >> 2);
  const int bkoff = (((t & 3) ^ (((t >> 2) >> 1) & 3)) << 3);
  const int blbase = (t & 448) * 16;

#define STAGE_D(BUF, K0) do {                                                     \
    async16(smem + (BUF) + albase0,        Ap + (size_t)amrow[0] * K + (K0) + akoff[0]); \
    async16(smem + (BUF) + albase1,        Ap + (size_t)amrow[1] * K + (K0) + akoff[1]); \
    async16(smem + (BUF) + 16384 + blbase, Bp + (size_t)bmrow * K + (K0) + bkoff); \
  } while (0)

#define COMPUTE_D(BUF) do {                                                       \
    bf16x8 af[4], bfr[4];                                                         \
    _Pragma("unroll")                                                             \
    for (int fm = 0; fm < 4; ++fm) {                                              \
      const int m = wm * 64 + fm * 16 + lcol;                                     \
      af[fm] = *(const bf16x8*)(smem + (BUF) + m * 64 + (((lk ^ ((m >> 1) & 3)) & 3) << 4)); \
    }                                                                             \
    _Pragma("unroll")                                                             \
    for (int fn = 0; fn < 4; ++fn) {                                              \
      const int n = wn * 64 + fn * 16 + lcol;                                     \
      bfr[fn] = *(const bf16x8*)(smem + (BUF) + 16384 + n * 64 + (((lk ^ ((n >> 1) & 3)) & 3) << 4)); \
    }                                                                             \
    _Pragma("unroll")                                                             \
    for (int fm = 0; fm < 4; ++fm)                                                \
      _Pragma("unroll")                                                           \
      for (int fn = 0; fn < 4; ++fn)                                              \
        acc[fm][fn] = __builtin_amdgcn_mfma_f32_16x16x32_bf16(af[fm], bfr[fn], acc[fm][fn], 0, 0, 0); \
  } while (0)

  const int kb = kbeg * 32;
  STAGE_D(0, kb);
  for (int it = 0; it < 21; ++it) {
    STAGE_D(24576, kb + (2 * it + 1) * 32);
    VWAIT_BAR(3);
    COMPUTE_D(0);
    VBAR();
    STAGE_D(0, kb + (2 * it + 2) * 32);
    VWAIT_BAR(3);
    COMPUTE_D(24576);
    VBAR();
  }
  STAGE_D(24576, kb + 43 * 32);
  VWAIT_BAR(3);
  COMPUTE_D(0);
  VBAR();
  VWAIT_BAR(0);
  COMPUTE_D(24576);
#undef STAGE_D
#undef COMPUTE_D

  #pragma unroll
  for (int fm = 0; fm < 4; ++fm) {
    #pragma unroll
    for (int fn = 0; fn < 4; ++fn) {
      const int col = n0 + wn * 64 + fn * 16 + lcol;
      #pragma unroll
      for (int r = 0; r < 4; ++r) {
        const int lrow = wm * 64 + fm * 16 + lk * 4 + r;
        if (lrow < mcnt) {
          const float v = acc[fm][fn][r];
          const int sl = rowbase + lrow;
          const int orow = em ? list[sl] : sl;
          const float sc = em ? wl[sl] : sg[sl];
          atomicAdd(out + (size_t)orow * HDIM + col, sc * v);
        }
      }
    }
  }
}

extern "C" void kernel_launch(void* const* d_in, const int* in_sizes, int n_in,
                              void* d_out, int out_size, void* d_ws, size_t ws_size,
                              hipStream_t stream)
{
  const float* x       = (const float*)d_in[0];
  const float* gate_w  = (const float*)d_in[1];
  const float* w_gate  = (const float*)d_in[2];
  const float* w_up    = (const float*)d_in[3];
  const float* w_down  = (const float*)d_in[4];
  const float* sw_gate = (const float*)d_in[5];
  const float* sw_up   = (const float*)d_in[6];
  const float* sw_down = (const float*)d_in[7];
  const float* sgw     = (const float*)d_in[8];

  float* out = (float*)d_out;   // f32 [TOK][H]; pure accumulator (zeroed)
  char* ws = (char*)d_ws;

  const size_t NEED_OVL   = 251100000;   // overlapped-transpose layout (~251 MB)
  const size_t NEED_FUSED = 182000000;   // r10 layout

  if (ws_size >= NEED_OVL) {
    unsigned short* Xb  = (unsigned short*)ws;                      //   8,388,608
    unsigned short* W1  = (unsigned short*)(ws + 8388608);          //  23,068,672 shG^T
    unsigned short* W2  = (unsigned short*)(ws + 31457280);         //  23,068,672 shU^T
    unsigned short* W3  = (unsigned short*)(ws + 54525952);         //  46,137,344 exG^T
    unsigned short* W4  = (unsigned short*)(ws + 100663296);        //  46,137,344 exU^T
    unsigned short* W5  = (unsigned short*)(ws + 146800640);        //  23,068,672 shDown^T
    unsigned short* W6  = (unsigned short*)(ws + 169869312);        //  46,137,344 exDown^T
    unsigned short* shb = (unsigned short*)(ws + 216006656);        //  23,068,672
    unsigned short* hb  = (unsigned short*)(ws + 239075328);        //  11,894,784
    char* meta = ws + 250970112;
    int*   cnt   = (int*)(meta);
    int*   cur   = (int*)(meta + 256);
    int*   offs  = (int*)(meta + 512);
    int*   list  = (int*)(meta + 768);                 // 4608 ints (zero-padded)
    float* wl    = (float*)(meta + 768 + 18432);       // 4608 floats (zero-padded)
    int*   tok_e = (int*)(meta + 768 + 2 * 18432);
    float* tok_w = (float*)(meta + 768 + 2 * 18432 + 16384);
    float* sg    = (float*)(meta + 768 + 2 * 18432 + 32768);

    hipMemsetAsync(meta, 0, 768 + 2 * 18432, stream);
    hipMemsetAsync(out, 0, (size_t)TOK * HDIM * 4, stream);

    cvt_kernel<<<TOK * HDIM / 4 / 512, 256, 0, stream>>>(x, Xb, TOK * HDIM / 4);
    router_kernel<<<TOK, 256, 0, stream>>>(x, gate_w, sgw, cnt, tok_e, tok_w, sg);
    scan_kernel<<<1, 64, 0, stream>>>(cnt, offs);
    build_kernel<<<8, 256, 0, stream>>>(tok_e, tok_w, offs, cur, list, wl);

    transpose_cvt_kernel<<<dim3(ISDIM / 64, HDIM / 64, 1), 256, 0, stream>>>(sw_gate, W1, HDIM, ISDIM);
    transpose_cvt_kernel<<<dim3(ISDIM / 64, HDIM / 64, 1), 256, 0, stream>>>(sw_up,   W2, HDIM, ISDIM);
    transpose_cvt_kernel<<<dim3(IDIM / 64, HDIM / 64, NEXP), 256, 0, stream>>>(w_gate, W3, HDIM, IDIM);
    transpose_cvt_kernel<<<dim3(IDIM / 64, HDIM / 64, NEXP), 256, 0, stream>>>(w_up,   W4, HDIM, IDIM);

    // 1088 GEMM blocks + 4224 fused-transpose blocks (sw_down->W5, w_down->W6)
    gateup_fused_kernel<<<GU_GEMM_BLOCKS + 4224, 512, 0, stream>>>(
        Xb, W1, W2, W3, W4, shb, hb, list, offs, cnt, sw_down, w_down, W5, W6);

    down_fused_kernel<<<1536, 512, 0, stream>>>(shb, hb, W5, W6, out, list, wl, sg, offs, cnt);
  } else if (ws_size >= NEED_FUSED) {
    // r10 layout: down-weight transposes overwrite W1/W3 after gateup
    unsigned short* Xb  = (unsigned short*)ws;
    unsigned short* W1  = (unsigned short*)(ws + 8388608);
    unsigned short* W2  = (unsigned short*)(ws + 31457280);
    unsigned short* W3  = (unsigned short*)(ws + 54525952);
    unsigned short* W4  = (unsigned short*)(ws + 100663296);
    unsigned short* shb = (unsigned short*)(ws + 146800640);
    unsigned short* hb  = (unsigned short*)(ws + 169869312);
    char* meta = ws + 181764096;
    int*   cnt   = (int*)(meta);
    int*   cur   = (int*)(meta + 256);
    int*   offs  = (int*)(meta + 512);
    int*   list  = (int*)(meta + 768);
    float* wl    = (float*)(meta + 768 + 18432);
    int*   tok_e = (int*)(meta + 768 + 2 * 18432);
    float* tok_w = (float*)(meta + 768 + 2 * 18432 + 16384);
    float* sg    = (float*)(meta + 768 + 2 * 18432 + 32768);

    hipMemsetAsync(meta, 0, 768 + 2 * 18432, stream);
    hipMemsetAsync(out, 0, (size_t)TOK * HDIM * 4, stream);

    cvt_kernel<<<TOK * HDIM / 4 / 512, 256, 0, stream>>>(x, Xb, TOK * HDIM / 4);
    router_kernel<<<TOK, 256, 0, stream>>>(x, gate_w, sgw, cnt, tok_e, tok_w, sg);
    scan_kernel<<<1, 64, 0, stream>>>(cnt, offs);
    build_kernel<<<8, 256, 0, stream>>>(tok_e, tok_w, offs, cur, list, wl);

    transpose_cvt_kernel<<<dim3(ISDIM / 64, HDIM / 64, 1), 256, 0, stream>>>(sw_gate, W1, HDIM, ISDIM);
    transpose_cvt_kernel<<<dim3(ISDIM / 64, HDIM / 64, 1), 256, 0, stream>>>(sw_up,   W2, HDIM, ISDIM);
    transpose_cvt_kernel<<<dim3(IDIM / 64, HDIM / 64, NEXP), 256, 0, stream>>>(w_gate, W3, HDIM, IDIM);
    transpose_cvt_kernel<<<dim3(IDIM / 64, HDIM / 64, NEXP), 256, 0, stream>>>(w_up,   W4, HDIM, IDIM);

    gateup_fused_kernel<<<GU_GEMM_BLOCKS, 512, 0, stream>>>(
        Xb, W1, W2, W3, W4, shb, hb, list, offs, cnt, nullptr, nullptr, nullptr, nullptr);

    transpose_cvt_kernel<<<dim3(HDIM / 64, ISDIM / 64, 1), 256, 0, stream>>>(sw_down, W1, ISDIM, HDIM);
    transpose_cvt_kernel<<<dim3(HDIM / 64, IDIM / 64, NEXP), 256, 0, stream>>>(w_down, W3, IDIM, HDIM);

    down_fused_kernel<<<1536, 512, 0, stream>>>(shb, hb, W1, W3, out, list, wl, sg, offs, cnt);
  }
}

// Round 14
// 585.962 us; speedup vs baseline: 1.0965x; 1.0025x over previous
//
#include <hip/hip_runtime.h>
#include <hip/hip_bf16.h>
#include <stdint.h>

// Qwen3.5 MoE block: router top-2 sparse dispatch + shared expert (SwiGLU), bf16 MFMA.
// B=2,S=1024 -> TOK=2048 tokens. H=2048, I=1408, IS=5632, E=8, K=2. Output f32.
// Round 14: gateup/down = round-10 exact (best measured: 206/205 us). All SIX
// weight transposes merged into ONE dispatch (descriptor-driven) -> no serial
// tails, max parallelism, pure-HBM pass up front.
#define TOK   2048
#define HDIM  2048
#define IDIM  1408
#define ISDIM 5632
#define NEXP  8

typedef float  f32x4  __attribute__((ext_vector_type(4)));
typedef short  bf16x8 __attribute__((ext_vector_type(8)));

__device__ __forceinline__ unsigned short f2b(float f) {
  union { float f; uint32_t u; } v; v.f = f;
  return (unsigned short)((v.u + 0x7fffu + ((v.u >> 16) & 1u)) >> 16); // RNE
}

// async global->LDS DMA, 16 B per lane: LDS dest wave-uniform base + lane*16.
__device__ __forceinline__ void async16(void* lds, const void* g) {
  __builtin_amdgcn_global_load_lds(
      (const __attribute__((address_space(1))) unsigned int*)g,
      (__attribute__((address_space(3))) unsigned int*)lds, 16, 0, 0);
}

// counted-vmcnt + raw barrier (no lgkm/vm drain); "memory" clobber pins LDS/VMEM ops.
#define VWAIT_BAR(N) asm volatile("s_waitcnt vmcnt(" #N ")\n\ts_barrier" ::: "memory")
#define VBAR()       asm volatile("s_barrier" ::: "memory")

// ---------------- router ----------------
__global__ __launch_bounds__(256) void router_kernel(
    const float* __restrict__ X, const float* __restrict__ GW,
    const float* __restrict__ SGW, int* __restrict__ cnt,
    int* __restrict__ tok_e, float* __restrict__ tok_w, float* __restrict__ sg)
{
  const int tkn = blockIdx.x, t = threadIdx.x;
  const float* xr = X + (size_t)tkn * HDIM;
  float a[NEXP + 1];
  #pragma unroll
  for (int e = 0; e <= NEXP; ++e) a[e] = 0.f;
  for (int h = t; h < HDIM; h += 256) {
    const float xv = xr[h];
    #pragma unroll
    for (int e = 0; e < NEXP; ++e) a[e] += xv * GW[e * HDIM + h];
    a[NEXP] += xv * SGW[h];
  }
  #pragma unroll
  for (int off = 32; off > 0; off >>= 1) {
    #pragma unroll
    for (int e = 0; e <= NEXP; ++e) a[e] += __shfl_down(a[e], off);
  }
  __shared__ float red[4][NEXP + 1];
  if ((t & 63) == 0) {
    #pragma unroll
    for (int e = 0; e <= NEXP; ++e) red[t >> 6][e] = a[e];
  }
  __syncthreads();
  if (t == 0) {
    float l[NEXP + 1];
    #pragma unroll
    for (int e = 0; e <= NEXP; ++e) l[e] = red[0][e] + red[1][e] + red[2][e] + red[3][e];
    int i1 = 0;
    #pragma unroll
    for (int e = 1; e < NEXP; ++e) if (l[e] > l[i1]) i1 = e;
    int i2 = (i1 == 0) ? 1 : 0;
    #pragma unroll
    for (int e = 0; e < NEXP; ++e) if (e != i1 && e != i2 && l[e] > l[i2]) i2 = e;
    const float w1 = 1.f / (1.f + __expf(l[i2] - l[i1]));   // softmax+top2+renorm == sigmoid(diff)
    tok_e[tkn * 2 + 0] = i1; tok_e[tkn * 2 + 1] = i2;
    tok_w[tkn * 2 + 0] = w1; tok_w[tkn * 2 + 1] = 1.f - w1;
    atomicAdd(&cnt[i1], 1); atomicAdd(&cnt[i2], 1);
    sg[tkn] = 1.f / (1.f + __expf(-l[NEXP]));
  }
}

__global__ void scan_kernel(const int* __restrict__ cnt, int* __restrict__ offs) {
  if (threadIdx.x == 0) {
    int r = 0;
    for (int e = 0; e < NEXP; ++e) { offs[e] = r; r += cnt[e]; }
  }
}

__global__ __launch_bounds__(256) void build_kernel(
    const int* __restrict__ tok_e, const float* __restrict__ tok_w,
    const int* __restrict__ offs, int* __restrict__ cur,
    int* __restrict__ list, float* __restrict__ wl)
{
  const int tkn = blockIdx.x * 256 + threadIdx.x;
  if (tkn >= TOK) return;
  #pragma unroll
  for (int k = 0; k < 2; ++k) {
    const int e = tok_e[tkn * 2 + k];
    const int pos = atomicAdd(&cur[e], 1);
    const int slot = offs[e] + pos;
    list[slot] = tkn;
    wl[slot] = tok_w[tkn * 2 + k];
  }
}

// ---------------- preprocessing ----------------
__global__ __launch_bounds__(256) void cvt_kernel(
    const float* __restrict__ src, unsigned short* __restrict__ dst, int n4)
{
  const int i = blockIdx.x * 512 + threadIdx.x;
  #pragma unroll
  for (int p = 0; p < 2; ++p) {
    const int j = i + p * 256;
    if (j < n4) {
      const float4 v = ((const float4*)src)[j];
      ushort4 b; b.x = f2b(v.x); b.y = f2b(v.y); b.z = f2b(v.z); b.w = f2b(v.w);
      ((ushort4*)dst)[j] = b;
    }
  }
}

// legacy single-matrix transpose (fallback path). f32 [R][C] -> bf16 [C][R].
__global__ __launch_bounds__(256) void transpose_cvt_kernel(
    const float* __restrict__ src, unsigned short* __restrict__ dst,
    const int R, const int C)
{
  __shared__ unsigned short tile[64][72];
  const size_t mat = (size_t)blockIdx.z * R * C;
  const int c0 = blockIdx.x * 64, r0 = blockIdx.y * 64;
  const int t = threadIdx.x;
  const int rr = t >> 4, cc = (t & 15) * 4;
  #pragma unroll
  for (int p = 0; p < 4; ++p) {
    const int r = rr + p * 16;
    const float4 v = *(const float4*)(src + mat + (size_t)(r0 + r) * C + c0 + cc);
    tile[cc + 0][r] = f2b(v.x);
    tile[cc + 1][r] = f2b(v.y);
    tile[cc + 2][r] = f2b(v.z);
    tile[cc + 3][r] = f2b(v.w);
  }
  __syncthreads();
  #pragma unroll
  for (int p = 0; p < 2; ++p) {
    const int id = p * 256 + t;
    const int c = id >> 3, q = id & 7;
    const uint4 v = *(const uint4*)&tile[c][q * 8];
    *(uint4*)(dst + mat + (size_t)(c0 + c) * R + r0 + q * 8) = v;
  }
}

// ---------------- unified transpose: ALL 6 weight matrices in one dispatch ----------------
// Per block: one 64x64 tile. Descriptor ranges (25344 total):
//   [0,2816)      sw_gate [H][IS] -> W1 [IS][H]     cx%88, ry/88
//   [2816,5632)   sw_up           -> W2
//   [5632,11264)  w_gate  e:[H][I] -> W3 e:[I][H]   704/e, cx%22
//   [11264,16896) w_up            -> W4
//   [16896,19712) sw_down [IS][H] -> W5 [H][IS]     cx%32, ry/32
//   [19712,25344) w_down  e:[I][H] -> W6 e:[H][I]   704/e, cx%32
__global__ __launch_bounds__(256) void transpose_all_kernel(
    const float* __restrict__ sw_gate, const float* __restrict__ sw_up,
    const float* __restrict__ w_gate,  const float* __restrict__ w_up,
    const float* __restrict__ sw_down, const float* __restrict__ w_down,
    unsigned short* __restrict__ W1, unsigned short* __restrict__ W2,
    unsigned short* __restrict__ W3, unsigned short* __restrict__ W4,
    unsigned short* __restrict__ W5, unsigned short* __restrict__ W6)
{
  __shared__ unsigned short tile[64][72];
  int b = blockIdx.x;
  const float* src; unsigned short* dst;
  int srcC, dstLen, cx, ry;
  if (b < 2816)       { src = sw_gate; dst = W1; srcC = ISDIM; dstLen = HDIM; cx = b % 88; ry = b / 88; }
  else if (b < 5632)  { b -= 2816; src = sw_up; dst = W2; srcC = ISDIM; dstLen = HDIM; cx = b % 88; ry = b / 88; }
  else if (b < 11264) { b -= 5632; const int e = b / 704, r = b % 704;
                        src = w_gate + (size_t)e * HDIM * IDIM; dst = W3 + (size_t)e * IDIM * HDIM;
                        srcC = IDIM; dstLen = HDIM; cx = r % 22; ry = r / 22; }
  else if (b < 16896) { b -= 11264; const int e = b / 704, r = b % 704;
                        src = w_up + (size_t)e * HDIM * IDIM; dst = W4 + (size_t)e * IDIM * HDIM;
                        srcC = IDIM; dstLen = HDIM; cx = r % 22; ry = r / 22; }
  else if (b < 19712) { b -= 16896; src = sw_down; dst = W5; srcC = HDIM; dstLen = ISDIM; cx = b % 32; ry = b / 32; }
  else                { b -= 19712; const int e = b / 704, r = b % 704;
                        src = w_down + (size_t)e * IDIM * HDIM; dst = W6 + (size_t)e * HDIM * IDIM;
                        srcC = HDIM; dstLen = IDIM; cx = r % 32; ry = r / 32; }

  const int c0 = cx * 64, r0 = ry * 64;
  const int t = threadIdx.x;
  const int rr = t >> 4, cc = (t & 15) * 4;
  #pragma unroll
  for (int p = 0; p < 4; ++p) {
    const int r = rr + p * 16;
    const float4 v = *(const float4*)(src + (size_t)(r0 + r) * srcC + c0 + cc);
    tile[cc + 0][r] = f2b(v.x);
    tile[cc + 1][r] = f2b(v.y);
    tile[cc + 2][r] = f2b(v.z);
    tile[cc + 3][r] = f2b(v.w);
  }
  __syncthreads();
  #pragma unroll
  for (int p = 0; p < 2; ++p) {
    const int id = p * 256 + t;
    const int ci = id >> 3, q = id & 7;
    *(uint4*)(dst + (size_t)(c0 + ci) * dstLen + r0 + q * 8) = *(const uint4*)&tile[ci][q * 8];
  }
}

// ---------------- FUSED gateup: 256x128 tile, 8 waves, BK=32, counted-vmcnt dbuf (r10) ----------------
__global__ __launch_bounds__(512) void gateup_fused_kernel(
    const unsigned short* __restrict__ Xb,
    const unsigned short* __restrict__ Wshg, const unsigned short* __restrict__ Wshu,
    const unsigned short* __restrict__ Wexg, const unsigned short* __restrict__ Wexu,
    unsigned short* __restrict__ shb, unsigned short* __restrict__ hb,
    const int* __restrict__ list, const int* __restrict__ offs, const int* __restrict__ cnt)
{
  __shared__ char smem[65536];

  const int xcd = blockIdx.x & 7;
  const int local = blockIdx.x >> 3;
  const int c = xcd + 8 * (local >> 3);
  const int mt = local & 7;
  if (c >= 132) return;
  const int t = threadIdx.x;

  int rowbase, mcnt, n0, N, gather;
  const unsigned short *Wg, *Wu;
  unsigned short* Cout;
  if (c < 44) {
    N = ISDIM; n0 = c * 128; rowbase = mt * 256; mcnt = 256; gather = 0;
    Wg = Wshg; Wu = Wshu; Cout = shb;
  } else {
    const int cE = c - 44;
    const int e = cE / 11, n = cE % 11;
    mcnt = cnt[e] - mt * 256;
    if (mcnt <= 0) return;
    N = IDIM; n0 = n * 128; rowbase = offs[e] + mt * 256; gather = 1;
    Wg = Wexg + (size_t)e * IDIM * HDIM;
    Wu = Wexu + (size_t)e * IDIM * HDIM;
    Cout = hb;
  }

  const int wid = t >> 6, lane = t & 63;
  const int wm = wid >> 1, wn = wid & 1;
  const int lcol = lane & 15, lk = lane >> 4;

  f32x4 accg[4][4], accu[4][4];
  #pragma unroll
  for (int i = 0; i < 4; ++i)
    #pragma unroll
    for (int j = 0; j < 4; ++j) { accg[i][j] = {0.f,0.f,0.f,0.f}; accu[i][j] = {0.f,0.f,0.f,0.f}; }

  int arow[2], akoff[2];
  #pragma unroll
  for (int p = 0; p < 2; ++p) {
    const int s = p * 512 + t;
    const int m = s >> 2;
    akoff[p] = (((s & 3) ^ ((m >> 1) & 3)) << 3);
    arow[p] = gather ? list[rowbase + m] : (rowbase + m);   // list zero-padded (4608)
  }
  const int albase0 = (t & 448) * 16;
  const int albase1 = (512 + (t & 448)) * 16;
  const int bmrow = n0 + (t >> 2);
  const int bkoff = (((t & 3) ^ (((t >> 2) >> 1) & 3)) << 3);
  const int blbase = (t & 448) * 16;

#define STAGE_GU(BUF, K0) do {                                                    \
    async16(smem + (BUF) + albase0,        Xb + (size_t)arow[0] * HDIM + (K0) + akoff[0]); \
    async16(smem + (BUF) + albase1,        Xb + (size_t)arow[1] * HDIM + (K0) + akoff[1]); \
    async16(smem + (BUF) + 16384 + blbase, Wg + (size_t)bmrow * HDIM + (K0) + bkoff); \
    async16(smem + (BUF) + 24576 + blbase, Wu + (size_t)bmrow * HDIM + (K0) + bkoff); \
  } while (0)

#define COMPUTE_GU(BUF) do {                                                      \
    bf16x8 af[4], bg[4], bu[4];                                                   \
    _Pragma("unroll")                                                             \
    for (int fm = 0; fm < 4; ++fm) {                                              \
      const int m = wm * 64 + fm * 16 + lcol;                                     \
      af[fm] = *(const bf16x8*)(smem + (BUF) + m * 64 + (((lk ^ ((m >> 1) & 3)) & 3) << 4)); \
    }                                                                             \
    _Pragma("unroll")                                                             \
    for (int fn = 0; fn < 4; ++fn) {                                              \
      const int n = wn * 64 + fn * 16 + lcol;                                     \
      const int ra = n * 64 + (((lk ^ ((n >> 1) & 3)) & 3) << 4);                 \
      bg[fn] = *(const bf16x8*)(smem + (BUF) + 16384 + ra);                       \
      bu[fn] = *(const bf16x8*)(smem + (BUF) + 24576 + ra);                       \
    }                                                                             \
    _Pragma("unroll")                                                             \
    for (int fm = 0; fm < 4; ++fm)                                                \
      _Pragma("unroll")                                                           \
      for (int fn = 0; fn < 4; ++fn) {                                            \
        accg[fm][fn] = __builtin_amdgcn_mfma_f32_16x16x32_bf16(af[fm], bg[fn], accg[fm][fn], 0, 0, 0); \
        accu[fm][fn] = __builtin_amdgcn_mfma_f32_16x16x32_bf16(af[fm], bu[fn], accu[fm][fn], 0, 0, 0); \
      } } while (0)

  STAGE_GU(0, 0);
  for (int it = 0; it < 31; ++it) {
    STAGE_GU(32768, (2 * it + 1) * 32);
    VWAIT_BAR(4);
    COMPUTE_GU(0);
    VBAR();
    STAGE_GU(0, (2 * it + 2) * 32);
    VWAIT_BAR(4);
    COMPUTE_GU(32768);
    VBAR();
  }
  STAGE_GU(32768, 63 * 32);
  VWAIT_BAR(4);
  COMPUTE_GU(0);
  VBAR();
  VWAIT_BAR(0);
  COMPUTE_GU(32768);
#undef STAGE_GU
#undef COMPUTE_GU

  #pragma unroll
  for (int fm = 0; fm < 4; ++fm) {
    #pragma unroll
    for (int fn = 0; fn < 4; ++fn) {
      const int col = n0 + wn * 64 + fn * 16 + lcol;
      #pragma unroll
      for (int r = 0; r < 4; ++r) {
        const int lrow = wm * 64 + fm * 16 + lk * 4 + r;
        if (lrow < mcnt) {
          const float gv = accg[fm][fn][r];
          const float uv = accu[fm][fn][r];
          const float hv = gv * uv / (1.f + __expf(-gv));
          Cout[(size_t)(rowbase + lrow) * N + col] = f2b(hv);
        }
      }
    }
  }
}

// ---------------- FUSED down: r10 verbatim (256x128, 2-buffer 48KB, vmcnt(3)) ----------------
__global__ __launch_bounds__(512) void down_fused_kernel(
    const unsigned short* __restrict__ shb, const unsigned short* __restrict__ hb,
    const unsigned short* __restrict__ WdshT, const unsigned short* __restrict__ WdexT,
    float* __restrict__ out,
    const int* __restrict__ list, const float* __restrict__ wl, const float* __restrict__ sg,
    const int* __restrict__ offs, const int* __restrict__ cnt)
{
  __shared__ char smem[49152];

  const int xcd = blockIdx.x & 7;
  const int local = blockIdx.x >> 3;
  const int c = xcd + 8 * (local >> 3);   // 0..191
  const int mt = local & 7;
  const int t = threadIdx.x;

  int rowbase, mcnt, n0, K, kbeg, em;
  const unsigned short *Ap, *Bp;
  if (c < 64) {                // shared, splitK=4 (44 steps each)
    const int pn = c & 15, ksp = c >> 4;
    rowbase = mt * 256; mcnt = 256; n0 = pn * 128;
    K = ISDIM; kbeg = ksp * 44; em = 0;
    Ap = shb; Bp = WdshT;
  } else {                     // expert (44 steps)
    const int cE = c - 64;
    const int e = cE >> 4, n = cE & 15;
    mcnt = cnt[e] - mt * 256;
    if (mcnt <= 0) return;
    rowbase = offs[e] + mt * 256; n0 = n * 128;
    K = IDIM; kbeg = 0; em = 1;
    Ap = hb; Bp = WdexT + (size_t)e * HDIM * IDIM;
  }

  const int wid = t >> 6, lane = t & 63;
  const int wm = wid >> 1, wn = wid & 1;
  const int lcol = lane & 15, lk = lane >> 4;

  f32x4 acc[4][4];
  #pragma unroll
  for (int i = 0; i < 4; ++i)
    #pragma unroll
    for (int j = 0; j < 4; ++j) acc[i][j] = {0.f,0.f,0.f,0.f};

  int amrow[2], akoff[2];
  #pragma unroll
  for (int p = 0; p < 2; ++p) {
    const int s = p * 512 + t;
    const int m = s >> 2;
    akoff[p] = (((s & 3) ^ ((m >> 1) & 3)) << 3);
    int rw = rowbase + m;
    if (em && rw > 4223) rw = 4223;    // clamp: hb has 4224 row slots
    amrow[p] = rw;
  }
  const int albase0 = (t & 448) * 16;
  const int albase1 = (512 + (t & 448)) * 16;
  const int bmrow = n0 + (t >> 2);
  const int bkoff = (((t & 3) ^ (((t >> 2) >> 1) & 3)) << 3);
  const int blbase = (t & 448) * 16;

#define STAGE_D(BUF, K0) do {                                                     \
    async16(smem + (BUF) + albase0,        Ap + (size_t)amrow[0] * K + (K0) + akoff[0]); \
    async16(smem + (BUF) + albase1,        Ap + (size_t)amrow[1] * K + (K0) + akoff[1]); \
    async16(smem + (BUF) + 16384 + blbase, Bp + (size_t)bmrow * K + (K0) + bkoff); \
  } while (0)

#define COMPUTE_D(BUF) do {                                                       \
    bf16x8 af[4], bfr[4];                                                         \
    _Pragma("unroll")                                                             \
    for (int fm = 0; fm < 4; ++fm) {                                              \
      const int m = wm * 64 + fm * 16 + lcol;                                     \
      af[fm] = *(const bf16x8*)(smem + (BUF) + m * 64 + (((lk ^ ((m >> 1) & 3)) & 3) << 4)); \
    }                                                                             \
    _Pragma("unroll")                                                             \
    for (int fn = 0; fn < 4; ++fn) {                                              \
      const int n = wn * 64 + fn * 16 + lcol;                                     \
      bfr[fn] = *(const bf16x8*)(smem + (BUF) + 16384 + n * 64 + (((lk ^ ((n >> 1) & 3)) & 3) << 4)); \
    }                                                                             \
    _Pragma("unroll")                                                             \
    for (int fm = 0; fm < 4; ++fm)                                                \
      _Pragma("unroll")                                                           \
      for (int fn = 0; fn < 4; ++fn)                                              \
        acc[fm][fn] = __builtin_amdgcn_mfma_f32_16x16x32_bf16(af[fm], bfr[fn], acc[fm][fn], 0, 0, 0); \
  } while (0)

  const int kb = kbeg * 32;
  STAGE_D(0, kb);
  for (int it = 0; it < 21; ++it) {
    STAGE_D(24576, kb + (2 * it + 1) * 32);
    VWAIT_BAR(3);
    COMPUTE_D(0);
    VBAR();
    STAGE_D(0, kb + (2 * it + 2) * 32);
    VWAIT_BAR(3);
    COMPUTE_D(24576);
    VBAR();
  }
  STAGE_D(24576, kb + 43 * 32);
  VWAIT_BAR(3);
  COMPUTE_D(0);
  VBAR();
  VWAIT_BAR(0);
  COMPUTE_D(24576);
#undef STAGE_D
#undef COMPUTE_D

  #pragma unroll
  for (int fm = 0; fm < 4; ++fm) {
    #pragma unroll
    for (int fn = 0; fn < 4; ++fn) {
      const int col = n0 + wn * 64 + fn * 16 + lcol;
      #pragma unroll
      for (int r = 0; r < 4; ++r) {
        const int lrow = wm * 64 + fm * 16 + lk * 4 + r;
        if (lrow < mcnt) {
          const float v = acc[fm][fn][r];
          const int sl = rowbase + lrow;
          const int orow = em ? list[sl] : sl;
          const float sc = em ? wl[sl] : sg[sl];
          atomicAdd(out + (size_t)orow * HDIM + col, sc * v);
        }
      }
    }
  }
}

extern "C" void kernel_launch(void* const* d_in, const int* in_sizes, int n_in,
                              void* d_out, int out_size, void* d_ws, size_t ws_size,
                              hipStream_t stream)
{
  const float* x       = (const float*)d_in[0];
  const float* gate_w  = (const float*)d_in[1];
  const float* w_gate  = (const float*)d_in[2];
  const float* w_up    = (const float*)d_in[3];
  const float* w_down  = (const float*)d_in[4];
  const float* sw_gate = (const float*)d_in[5];
  const float* sw_up   = (const float*)d_in[6];
  const float* sw_down = (const float*)d_in[7];
  const float* sgw     = (const float*)d_in[8];

  float* out = (float*)d_out;   // f32 [TOK][H]; pure accumulator (zeroed)
  char* ws = (char*)d_ws;

  const size_t NEED_OVL   = 251100000;   // all-weights layout (~251 MB)
  const size_t NEED_FUSED = 182000000;   // r10 layout

  if (ws_size >= NEED_OVL) {
    unsigned short* Xb  = (unsigned short*)ws;                      //   8,388,608
    unsigned short* W1  = (unsigned short*)(ws + 8388608);          //  23,068,672 shG^T
    unsigned short* W2  = (unsigned short*)(ws + 31457280);         //  23,068,672 shU^T
    unsigned short* W3  = (unsigned short*)(ws + 54525952);         //  46,137,344 exG^T
    unsigned short* W4  = (unsigned short*)(ws + 100663296);        //  46,137,344 exU^T
    unsigned short* W5  = (unsigned short*)(ws + 146800640);        //  23,068,672 shDown^T
    unsigned short* W6  = (unsigned short*)(ws + 169869312);        //  46,137,344 exDown^T
    unsigned short* shb = (unsigned short*)(ws + 216006656);        //  23,068,672
    unsigned short* hb  = (unsigned short*)(ws + 239075328);        //  11,894,784
    char* meta = ws + 250970112;
    int*   cnt   = (int*)(meta);
    int*   cur   = (int*)(meta + 256);
    int*   offs  = (int*)(meta + 512);
    int*   list  = (int*)(meta + 768);                 // 4608 ints (zero-padded)
    float* wl    = (float*)(meta + 768 + 18432);       // 4608 floats (zero-padded)
    int*   tok_e = (int*)(meta + 768 + 2 * 18432);
    float* tok_w = (float*)(meta + 768 + 2 * 18432 + 16384);
    float* sg    = (float*)(meta + 768 + 2 * 18432 + 32768);

    hipMemsetAsync(meta, 0, 768 + 2 * 18432, stream);
    hipMemsetAsync(out, 0, (size_t)TOK * HDIM * 4, stream);

    cvt_kernel<<<TOK * HDIM / 4 / 512, 256, 0, stream>>>(x, Xb, TOK * HDIM / 4);
    router_kernel<<<TOK, 256, 0, stream>>>(x, gate_w, sgw, cnt, tok_e, tok_w, sg);
    scan_kernel<<<1, 64, 0, stream>>>(cnt, offs);
    build_kernel<<<8, 256, 0, stream>>>(tok_e, tok_w, offs, cur, list, wl);

    // ONE dispatch for all six weight transposes
    transpose_all_kernel<<<25344, 256, 0, stream>>>(
        sw_gate, sw_up, w_gate, w_up, sw_down, w_down, W1, W2, W3, W4, W5, W6);

    gateup_fused_kernel<<<1088, 512, 0, stream>>>(
        Xb, W1, W2, W3, W4, shb, hb, list, offs, cnt);

    down_fused_kernel<<<1536, 512, 0, stream>>>(shb, hb, W5, W6, out, list, wl, sg, offs, cnt);
  } else if (ws_size >= NEED_FUSED) {
    // r10 layout: down-weight transposes overwrite W1/W3 after gateup
    unsigned short* Xb  = (unsigned short*)ws;
    unsigned short* W1  = (unsigned short*)(ws + 8388608);
    unsigned short* W2  = (unsigned short*)(ws + 31457280);
    unsigned short* W3  = (unsigned short*)(ws + 54525952);
    unsigned short* W4  = (unsigned short*)(ws + 100663296);
    unsigned short* shb = (unsigned short*)(ws + 146800640);
    unsigned short* hb  = (unsigned short*)(ws + 169869312);
    char* meta = ws + 181764096;
    int*   cnt   = (int*)(meta);
    int*   cur   = (int*)(meta + 256);
    int*   offs  = (int*)(meta + 512);
    int*   list  = (int*)(meta + 768);
    float* wl    = (float*)(meta + 768 + 18432);
    int*   tok_e = (int*)(meta + 768 + 2 * 18432);
    float* tok_w = (float*)(meta + 768 + 2 * 18432 + 16384);
    float* sg    = (float*)(meta + 768 + 2 * 18432 + 32768);

    hipMemsetAsync(meta, 0, 768 + 2 * 18432, stream);
    hipMemsetAsync(out, 0, (size_t)TOK * HDIM * 4, stream);

    cvt_kernel<<<TOK * HDIM / 4 / 512, 256, 0, stream>>>(x, Xb, TOK * HDIM / 4);
    router_kernel<<<TOK, 256, 0, stream>>>(x, gate_w, sgw, cnt, tok_e, tok_w, sg);
    scan_kernel<<<1, 64, 0, stream>>>(cnt, offs);
    build_kernel<<<8, 256, 0, stream>>>(tok_e, tok_w, offs, cur, list, wl);

    transpose_cvt_kernel<<<dim3(ISDIM / 64, HDIM / 64, 1), 256, 0, stream>>>(sw_gate, W1, HDIM, ISDIM);
    transpose_cvt_kernel<<<dim3(ISDIM / 64, HDIM / 64, 1), 256, 0, stream>>>(sw_up,   W2, HDIM, ISDIM);
    transpose_cvt_kernel<<<dim3(IDIM / 64, HDIM / 64, NEXP), 256, 0, stream>>>(w_gate, W3, HDIM, IDIM);
    transpose_cvt_kernel<<<dim3(IDIM / 64, HDIM / 64, NEXP), 256, 0, stream>>>(w_up,   W4, HDIM, IDIM);

    gateup_fused_kernel<<<1088, 512, 0, stream>>>(
        Xb, W1, W2, W3, W4, shb, hb, list, offs, cnt);

    transpose_cvt_kernel<<<dim3(HDIM / 64, ISDIM / 64, 1), 256, 0, stream>>>(sw_down, W1, ISDIM, HDIM);
    transpose_cvt_kernel<<<dim3(HDIM / 64, IDIM / 64, NEXP), 256, 0, stream>>>(w_down, W3, IDIM, HDIM);

    down_fused_kernel<<<1536, 512, 0, stream>>>(shb, hb, W1, W3, out, list, wl, sg, offs, cnt);
  }
}